// Round 9
// baseline (228.769 us; speedup 1.0000x reference)
//
#include <hip/hip_runtime.h>
#include <hip/hip_bf16.h>

// MultiHeadAttention  B=2, S=2048, D=1024, H=16, Dh=64  (fp32 I/O)
// Round 9:
//  - gemm_body: r8-verified double-buffer/single-barrier K-loop (unrolled x2,
//    compile-time buffer indices -> immediate ds offsets).
//  - attn: kt-loop unrolled x2 (compile-time buffers), swizzle offsets hoisted.
//  - gemm_fin: 1D grid, n-tile in low bits (weight XCD/L2 locality).

#define SEQ     2048
#define DMODEL  1024
#define NHEADS  16
#define DH      64
#define MROWS   4096
#define M1      (1024*1024)
#define M4      (4*1024*1024)
#define SCQ     0.18033688f      // log2(e)/sqrt(64)

typedef __hip_bfloat16 bf16;
typedef __attribute__((ext_vector_type(8))) short  short8;  // 8 bf16 = 4 VGPR
typedef __attribute__((ext_vector_type(4))) float  f32x4;   // MFMA C/D

__device__ __forceinline__ bf16 f2b(float x) { return __float2bfloat16(x); }
__device__ __forceinline__ f32x4 mfma16(short8 a, short8 b, f32x4 c) {
    return __builtin_amdgcn_mfma_f32_16x16x32_bf16(a, b, c, 0, 0, 0);
}
__device__ __forceinline__ unsigned pk2(float a, float b) {
    union { __hip_bfloat162 h; unsigned u; } x;
    x.h = __float22bfloat162_rn(float2{a, b});
    return x.u;
}
__device__ __forceinline__ short8 pk8(float4 a, float4 b) {
    union { short8 s; unsigned u[4]; } x;
    x.u[0] = pk2(a.x, a.y); x.u[1] = pk2(a.z, a.w);
    x.u[2] = pk2(b.x, b.y); x.u[3] = pk2(b.z, b.w);
    return x.s;
}
__device__ __forceinline__ float fexp2(float x) {
    return __builtin_amdgcn_exp2f(x);     // raw v_exp_f32
}
#define GLDS(g, l) __builtin_amdgcn_global_load_lds( \
    (const __attribute__((address_space(1))) void*)(g), \
    (__attribute__((address_space(3))) void*)(l), 16, 0, 0)

// ---------------------------------------------------------------------------
// fp32 -> bf16 conversion kernels
// ---------------------------------------------------------------------------
__global__ __launch_bounds__(256) void cvt_all(
    const float* __restrict__ Wq, const float* __restrict__ Wk,
    const float* __restrict__ Wv, const float* __restrict__ Wo,
    const float* __restrict__ Q,  const float* __restrict__ K,
    const float* __restrict__ V,  bf16* __restrict__ dst)
{
    const size_t gid = (size_t)blockIdx.x * 256 + threadIdx.x;   // 2M threads
    const size_t e0 = gid * 8;
    const float* s;
    if (e0 < (size_t)4 * M1) {
        const float* w[4] = {Wq, Wk, Wv, Wo};
        s = w[e0 >> 20] + (e0 & (M1 - 1));
    } else {
        const float* a[4] = {nullptr, Q, K, V};
        s = a[e0 >> 22] + (e0 & (M4 - 1));
    }
    float4 x = *(const float4*)s, y = *(const float4*)(s + 4);
    *(short8*)((short*)dst + e0) = pk8(x, y);
}

__global__ __launch_bounds__(256) void cvt_w(
    const float* __restrict__ W0, const float* __restrict__ W1,
    const float* __restrict__ W2, const float* __restrict__ W3,
    bf16* __restrict__ dst)
{
    const int gid = blockIdx.x * 256 + threadIdx.x;
    const int t   = gid >> 17;
    const int off = (gid & 131071) * 8;
    const float* srcs[4] = {W0, W1, W2, W3};
    const float* s = srcs[t] + off;
    float4 a = *(const float4*)s, b = *(const float4*)(s + 4);
    *(short8*)((short*)dst + (size_t)gid * 8) = pk8(a, b);
}

__global__ __launch_bounds__(256) void cvt_1(
    const float* __restrict__ X, bf16* __restrict__ D)
{
    const int gid = blockIdx.x * 256 + threadIdx.x;
    const int off = gid * 8;
    float4 a = *(const float4*)(X + off), b = *(const float4*)(X + off + 4);
    *(short8*)((short*)D + off) = pk8(a, b);
}

// ---------------------------------------------------------------------------
// bf16 MFMA GEMM body: C[m,n] = sum_k A[m,k]*B[n,k] + bias. 128xBN tile,
// BK=32, glds staging, DOUBLE-BUFFERED LDS, one barrier per K-step.
// mode: 0 fp32 flat; 1 bf16 heads [B,H,S,DH]; 2 bf16 heads-T [B,H,DH,S] with
// key-permutation tau within 32-groups (inverse realized by attn PV reads).
// ---------------------------------------------------------------------------
template <int BN>
__device__ __forceinline__ void gemm_body(
    const bf16* __restrict__ A, const bf16* __restrict__ B,
    const float* __restrict__ bias, void* __restrict__ outp,
    int m0, int n0, int mode, int bias_m, float scale)
{
    __shared__ short As[2][128 * 32];
    __shared__ short Bs[2][BN * 32];
    constexpr int NI = BN / 32;

    const int tid  = threadIdx.x;
    const int lane = tid & 63;
    const int wv   = tid >> 6;
    const int wm   = (wv >> 1) * 64;
    const int wn   = (wv & 1) * (BN / 2);
    const int fn   = lane & 15;
    const int fq   = lane >> 4;

    const int srow = lane >> 2;
    const int scol = (lane & 3) * 8;

    const short* Ag = (const short*)A;
    const short* Bg = (const short*)B;

    f32x4 acc[4][NI];
#pragma unroll
    for (int i = 0; i < 4; ++i)
#pragma unroll
        for (int j = 0; j < NI; ++j) acc[i][j] = (f32x4){0.f, 0.f, 0.f, 0.f};

    auto stage = [&](int k0, int buf) {
#pragma unroll
        for (int i = 0; i < 2; ++i) {
            const int rr = wv * 32 + i * 16;
            const short* ga = Ag + (size_t)(m0 + rr + srow) * DMODEL + k0 + scol;
            GLDS(ga, As[buf] + rr * 32);
        }
#pragma unroll
        for (int i = 0; i < BN / 64; ++i) {
            const int rr = wv * (BN / 4) + i * 16;
            const short* gb = Bg + (size_t)(n0 + rr + srow) * DMODEL + k0 + scol;
            GLDS(gb, Bs[buf] + rr * 32);
        }
    };

    auto compute = [&](const short* AsB, const short* BsB) {
        short8 af[4], bfr[NI];
#pragma unroll
        for (int im = 0; im < 4; ++im)
            af[im] = *(const short8*)(AsB + (wm + im * 16 + fn) * 32 + fq * 8);
#pragma unroll
        for (int in = 0; in < NI; ++in)
            bfr[in] = *(const short8*)(BsB + (wn + in * 16 + fn) * 32 + fq * 8);
#pragma unroll
        for (int im = 0; im < 4; ++im)
#pragma unroll
            for (int in = 0; in < NI; ++in)
                acc[im][in] = mfma16(af[im], bfr[in], acc[im][in]);
    };

    stage(0, 0);
#pragma unroll 1
    for (int k0 = 0; k0 < DMODEL; k0 += 64) {
        __syncthreads();                       // drains glds(buf0), prior reads done
        if (k0 + 32 < DMODEL) stage(k0 + 32, 1);
        compute(As[0], Bs[0]);
        __syncthreads();                       // drains glds(buf1)
        if (k0 + 64 < DMODEL) stage(k0 + 64, 0);
        compute(As[1], Bs[1]);
    }

#pragma unroll
    for (int im = 0; im < 4; ++im) {
#pragma unroll
        for (int in = 0; in < NI; ++in) {
#pragma unroll
            for (int r = 0; r < 4; ++r) {
                const int m = m0 + wm + im * 16 + fq * 4 + r;
                const int n = n0 + wn + in * 16 + fn;
                const float c = (acc[im][in][r] + (bias_m ? bias[m] : bias[n])) * scale;
                if (mode == 0) {
                    ((float*)outp)[(size_t)m * DMODEL + n] = c;
                } else if (mode == 1) {
                    const int b = m >> 11, s = m & (SEQ - 1);
                    const int h = n >> 6,  d = n & (DH - 1);
                    ((bf16*)outp)[(((size_t)(b * NHEADS + h) * SEQ) + s) * DH + d] = f2b(c);
                } else {
                    const int h = m >> 6,  d = m & (DH - 1);
                    const int b = n >> 11, s = n & (SEQ - 1);
                    const int p = s & 31;
                    const int sp = (s & ~31) | ((p & 12) << 1) | ((p & 16) >> 2) | (p & 3);
                    ((bf16*)outp)[(((size_t)(b * NHEADS + h) * DH) + d) * SEQ + sp] = f2b(c);
                }
            }
        }
    }
}

__global__ __launch_bounds__(256, 3) void gemm_one(
    const bf16* A, const bf16* B, const float* bias, void* out,
    int mode, int bias_m, float scale)
{
    gemm_body<128>(A, B, bias, out, blockIdx.x * 128, blockIdx.y * 128,
                   mode, bias_m, scale);
}

// 1D grid, n-tile in low 4 bits -> same-weight blocks cluster per XCD.
__global__ __launch_bounds__(256, 3) void gemm_fin(
    const bf16* A, const bf16* B, const float* bias, void* out)
{
    const int b = blockIdx.x;                 // 0..511
    gemm_body<64>(A, B, bias, out, (b >> 4) * 128, (b & 15) * 64, 0, 0, 1.f);
}

__global__ __launch_bounds__(256, 3) void gemm_qkv(
    const bf16* Qb, const bf16* Kb, const bf16* Vb, const bf16* Wb,
    const float* bq, const float* bk, const float* bv,
    bf16* qp, bf16* kp, bf16* vp)
{
    const int blk = blockIdx.x;
    const int z = blk >> 8, t = blk & 255;
    if (z == 0)
        gemm_body<128>(Qb, Wb,          bq, qp, (t >> 3) * 128, (t & 7) * 128, 1, 0, SCQ);
    else if (z == 1)
        gemm_body<128>(Kb, Wb + M1,     bk, kp, (t >> 3) * 128, (t & 7) * 128, 1, 0, 1.f);
    else
        gemm_body<128>(Wb + 2 * M1, Vb, bv, vp, (t >> 5) * 128, (t & 31) * 128, 2, 1, 1.f);
}

// ---------------------------------------------------------------------------
// MFMA flash attention. q,k: [B,H,S,DH] bf16 (q pre-scaled by log2e/8);
// vt: [B,H,DH,S] bf16, key-permuted (tau). out: concat [B,S,DMODEL] bf16.
// Double-buffered K/V staging, one barrier per K-tile, kt-loop unrolled x2
// (compile-time buffers, hoisted swizzle offsets); raw v_exp_f32 softmax;
// l via ones-row MFMA; XCD-swizzled grid.
// ---------------------------------------------------------------------------
__global__ __launch_bounds__(256) void attn_mfma(
    const bf16* __restrict__ q,
    const bf16* __restrict__ k,
    const bf16* __restrict__ vt,
    bf16* __restrict__ out)
{
    __shared__ short Kt[2][64 * 64];    // [buf][key][d]   rows 128B, swizzled chunks
    __shared__ short Vt[2][64 * 64];    // [buf][d][key']  rows 128B, swizzled

    const int tid  = threadIdx.x;
    const int wave = tid >> 6;
    const int lane = tid & 63;
    const int n    = lane & 15;
    const int quad = lane >> 4;

    const int blk  = blockIdx.x;          // 0..511
    const int xcd  = blk & 7;
    const int rest = blk >> 3;
    const int qt   = rest & 15;
    const int bh   = ((rest >> 4) << 3) | xcd;
    const int q0w  = qt * 128 + wave * 32;

    const bf16* qhead = q  + (size_t)bh * SEQ * DH;
    const bf16* khead = k  + (size_t)bh * SEQ * DH;
    const bf16* vhead = vt + (size_t)bh * DH * SEQ;

    short8 qf[2][2];
#pragma unroll
    for (int qg = 0; qg < 2; ++qg) {
        const short* qr = (const short*)(qhead + (size_t)(q0w + qg * 16 + n) * DH);
        qf[qg][0] = *(const short8*)(qr + quad * 8);
        qf[qg][1] = *(const short8*)(qr + 32 + quad * 8);
    }

    const short8 onesv = {(short)0x3F80, (short)0x3F80, (short)0x3F80, (short)0x3F80,
                          (short)0x3F80, (short)0x3F80, (short)0x3F80, (short)0x3F80};
    const f32x4 Zv = (f32x4){0.f, 0.f, 0.f, 0.f};

    f32x4 O[4][2];
#pragma unroll
    for (int gd = 0; gd < 4; ++gd)
#pragma unroll
        for (int qg = 0; qg < 2; ++qg) O[gd][qg] = Zv;
    f32x4 lacc[2] = {Zv, Zv};

    const int srow = lane >> 3;
    const int schk = (lane & 7) ^ srow;
    // hoisted swizzled chunk offsets (V offsets coincide with K offsets)
    const int off0 = ((quad       ^ (n & 7)) * 8);
    const int off1 = (((4 + quad) ^ (n & 7)) * 8);

    auto stage = [&](int kt, int buf) {
        const int kbase = kt * 64;
#pragma unroll
        for (int i = 0; i < 2; ++i) {
            const int r = wave * 16 + i * 8 + srow;
            const char* gk = (const char*)(khead + (size_t)(kbase + r) * DH) + schk * 16;
            const char* gv = (const char*)(vhead + (size_t)r * SEQ + kbase) + schk * 16;
            GLDS(gk, Kt[buf] + (wave * 16 + i * 8) * 64);
            GLDS(gv, Vt[buf] + (wave * 16 + i * 8) * 64);
        }
    };

    auto tile_body = [&](const short* KtB, const short* VtB) {
        // S^T = K Q^T : lane reg r -> S^T[key=g*16+quad*4+r][q=qg*16+n]
        f32x4 st[4][2];
#pragma unroll
        for (int g = 0; g < 4; ++g) {
            const short* kr = KtB + (g * 16 + n) * 64;
            short8 kf0 = *(const short8*)(kr + off0);
            short8 kf1 = *(const short8*)(kr + off1);
#pragma unroll
            for (int qg = 0; qg < 2; ++qg) {
                f32x4 s = mfma16(kf0, qf[qg][0], Zv);
                s = mfma16(kf1, qf[qg][1], s);
                st[g][qg] = s;
            }
        }
        // p = exp2(st) (raw v_exp_f32), packed cvt; l via ones-row MFMA
        short8 bP[2][2];
#pragma unroll
        for (int t = 0; t < 2; ++t) {
#pragma unroll
            for (int qg = 0; qg < 2; ++qg) {
                union { short8 s8; unsigned u[4]; } bb;
                bb.u[0] = pk2(fexp2(st[2*t][qg][0]),   fexp2(st[2*t][qg][1]));
                bb.u[1] = pk2(fexp2(st[2*t][qg][2]),   fexp2(st[2*t][qg][3]));
                bb.u[2] = pk2(fexp2(st[2*t+1][qg][0]), fexp2(st[2*t+1][qg][1]));
                bb.u[3] = pk2(fexp2(st[2*t+1][qg][2]), fexp2(st[2*t+1][qg][3]));
                bP[t][qg] = bb.s8;
                lacc[qg] = mfma16(onesv, bP[t][qg], lacc[qg]);
            }
        }
        // O^T += V^T P^T : V tau-permuted -> contiguous b128 fragments
#pragma unroll
        for (int gd = 0; gd < 4; ++gd) {
            const short* vr = VtB + (gd * 16 + n) * 64;
            short8 vf0 = *(const short8*)(vr + off0);
            short8 vf1 = *(const short8*)(vr + off1);
#pragma unroll
            for (int qg = 0; qg < 2; ++qg) {
                O[gd][qg] = mfma16(vf0, bP[0][qg], O[gd][qg]);
                O[gd][qg] = mfma16(vf1, bP[1][qg], O[gd][qg]);
            }
        }
    };

    stage(0, 0);
#pragma unroll 1
    for (int kt = 0; kt < SEQ / 64; kt += 2) {
        __syncthreads();
        stage(kt + 1, 1);                       // kt+1 < 32 always (kt <= 30)
        tile_body(Kt[0], Vt[0]);
        __syncthreads();
        if (kt + 2 < SEQ / 64) stage(kt + 2, 0);
        tile_body(Kt[1], Vt[1]);
    }

    const float inv0 = 1.0f / lacc[0][0];
    const float inv1 = 1.0f / lacc[1][0];
    const int b = bh >> 4;
    const int h = bh & (NHEADS - 1);
#pragma unroll
    for (int gd = 0; gd < 4; ++gd) {
#pragma unroll
        for (int qg = 0; qg < 2; ++qg) {
            const float iv = qg ? inv1 : inv0;
            const int s = q0w + qg * 16 + n;
            uint2 o;
            o.x = pk2(O[gd][qg][0] * iv, O[gd][qg][1] * iv);
            o.y = pk2(O[gd][qg][2] * iv, O[gd][qg][3] * iv);
            *(uint2*)(out + ((size_t)(b * SEQ + s)) * DMODEL + h * DH + gd * 16 + quad * 4) = o;
        }
    }
}

// ---------------------------------------------------------------------------
extern "C" void kernel_launch(void* const* d_in, const int* in_sizes, int n_in,
                              void* d_out, int out_size, void* d_ws, size_t ws_size,
                              hipStream_t stream) {
    const float* Q  = (const float*)d_in[0];
    const float* K  = (const float*)d_in[1];
    const float* V  = (const float*)d_in[2];
    const float* Wq = (const float*)d_in[3];
    const float* Wk = (const float*)d_in[4];
    const float* Wv = (const float*)d_in[5];
    const float* Wo = (const float*)d_in[6];
    const float* bq = (const float*)d_in[7];
    const float* bk = (const float*)d_in[8];
    const float* bv = (const float*)d_in[9];
    const float* bo = (const float*)d_in[10];

    // kp/vp live in d_out (16MB) as scratch; final GEMM rewrites d_out fully.
    bf16* kp = (bf16*)d_out;
    bf16* vp = kp + M4;

    dim3 bb(256);
    dim3 gqk(MROWS / 128, DMODEL / 128);   // (32,8)
    dim3 gvv(DMODEL / 128, MROWS / 128);   // (8,32)

    if (ws_size >= (size_t)40 * 1024 * 1024) {
        // fused: Wb 8MB | Qb 8 | Kb 8 | Vb 8 | qp 8 = 40MB; ao aliases Qb
        bf16* Wb = (bf16*)d_ws;
        bf16* Qb = Wb + 4 * M1;
        bf16* Kb = Qb + M4;
        bf16* Vb = Kb + M4;
        bf16* qp = Vb + M4;
        bf16* ao = Qb;                     // Qb dead after gemm_qkv

        cvt_all<<<8192, bb, 0, stream>>>(Wq, Wk, Wv, Wo, Q, K, V, Wb);
        gemm_qkv<<<768, bb, 0, stream>>>(Qb, Kb, Vb, Wb, bq, bk, bv, qp, kp, vp);
        attn_mfma<<<512, bb, 0, stream>>>(qp, kp, vp, ao);
        gemm_fin<<<512, bb, 0, stream>>>(ao, Wb + 3 * M1, bo, d_out);
    } else {
        // sequential: Wb 8 + Xb 8 + qp 8 = 24MB; ao aliases Xb
        bf16* Wb = (bf16*)d_ws;
        bf16* Xb = Wb + 4 * M1;
        bf16* qp = Xb + M4;
        bf16* ao = Xb;                     // Xb dead after V-proj

        cvt_w<<<2048, bb, 0, stream>>>(Wq, Wk, Wv, Wo, Wb);
        cvt_1<<<2048, bb, 0, stream>>>(Q, Xb);
        gemm_one<<<gqk, bb, 0, stream>>>(Xb, Wb, bq, qp, 1, 0, SCQ);
        cvt_1<<<2048, bb, 0, stream>>>(K, Xb);
        gemm_one<<<gqk, bb, 0, stream>>>(Xb, Wb + M1, bk, kp, 1, 0, 1.f);
        cvt_1<<<2048, bb, 0, stream>>>(V, Xb);
        gemm_one<<<gvv, bb, 0, stream>>>(Wb + 2 * M1, Xb, bv, vp, 2, 1, 1.f);
        attn_mfma<<<512, bb, 0, stream>>>(qp, kp, vp, ao);
        gemm_fin<<<512, bb, 0, stream>>>(ao, Wb + 3 * M1, bo, d_out);
    }
}

// Round 10
// 216.639 us; speedup vs baseline: 1.0560x; 1.0560x over previous
//
#include <hip/hip_runtime.h>
#include <hip/hip_bf16.h>

// MultiHeadAttention  B=2, S=2048, D=1024, H=16, Dh=64  (fp32 I/O)
// Round 10:
//  - gemm_body reverted to r8 (single-buffer, 2-barrier) — r9 dbuf regressed.
//  - attention split-K (2-way over keys): 1024 blocks = 4/CU; no-max softmax
//    makes merge purely additive (out = (O0+O1)/(l0+l1)). Partial O stored
//    bf16 in dead Kb/Vb scratch, l fp32 in dead Wq region; small merge kernel.

#define SEQ     2048
#define DMODEL  1024
#define NHEADS  16
#define DH      64
#define MROWS   4096
#define M1      (1024*1024)
#define M4      (4*1024*1024)
#define SCQ     0.18033688f      // log2(e)/sqrt(64)

typedef __hip_bfloat16 bf16;
typedef __attribute__((ext_vector_type(8))) short  short8;  // 8 bf16 = 4 VGPR
typedef __attribute__((ext_vector_type(4))) float  f32x4;   // MFMA C/D

__device__ __forceinline__ bf16 f2b(float x) { return __float2bfloat16(x); }
__device__ __forceinline__ float u2f(unsigned short u) {
    union { unsigned int i; float f; } x; x.i = ((unsigned int)u) << 16; return x.f;
}
__device__ __forceinline__ f32x4 mfma16(short8 a, short8 b, f32x4 c) {
    return __builtin_amdgcn_mfma_f32_16x16x32_bf16(a, b, c, 0, 0, 0);
}
__device__ __forceinline__ unsigned pk2(float a, float b) {
    union { __hip_bfloat162 h; unsigned u; } x;
    x.h = __float22bfloat162_rn(float2{a, b});
    return x.u;
}
__device__ __forceinline__ short8 pk8(float4 a, float4 b) {
    union { short8 s; unsigned u[4]; } x;
    x.u[0] = pk2(a.x, a.y); x.u[1] = pk2(a.z, a.w);
    x.u[2] = pk2(b.x, b.y); x.u[3] = pk2(b.z, b.w);
    return x.s;
}
__device__ __forceinline__ float fexp2(float x) {
    return __builtin_amdgcn_exp2f(x);     // raw v_exp_f32
}
#define GLDS(g, l) __builtin_amdgcn_global_load_lds( \
    (const __attribute__((address_space(1))) void*)(g), \
    (__attribute__((address_space(3))) void*)(l), 16, 0, 0)

// ---------------------------------------------------------------------------
// fp32 -> bf16 conversion kernels
// ---------------------------------------------------------------------------
__global__ __launch_bounds__(256) void cvt_all(
    const float* __restrict__ Wq, const float* __restrict__ Wk,
    const float* __restrict__ Wv, const float* __restrict__ Wo,
    const float* __restrict__ Q,  const float* __restrict__ K,
    const float* __restrict__ V,  bf16* __restrict__ dst)
{
    const size_t gid = (size_t)blockIdx.x * 256 + threadIdx.x;   // 2M threads
    const size_t e0 = gid * 8;
    const float* s;
    if (e0 < (size_t)4 * M1) {
        const float* w[4] = {Wq, Wk, Wv, Wo};
        s = w[e0 >> 20] + (e0 & (M1 - 1));
    } else {
        const float* a[4] = {nullptr, Q, K, V};
        s = a[e0 >> 22] + (e0 & (M4 - 1));
    }
    float4 x = *(const float4*)s, y = *(const float4*)(s + 4);
    *(short8*)((short*)dst + e0) = pk8(x, y);
}

__global__ __launch_bounds__(256) void cvt_w(
    const float* __restrict__ W0, const float* __restrict__ W1,
    const float* __restrict__ W2, const float* __restrict__ W3,
    bf16* __restrict__ dst)
{
    const int gid = blockIdx.x * 256 + threadIdx.x;
    const int t   = gid >> 17;
    const int off = (gid & 131071) * 8;
    const float* srcs[4] = {W0, W1, W2, W3};
    const float* s = srcs[t] + off;
    float4 a = *(const float4*)s, b = *(const float4*)(s + 4);
    *(short8*)((short*)dst + (size_t)gid * 8) = pk8(a, b);
}

__global__ __launch_bounds__(256) void cvt_1(
    const float* __restrict__ X, bf16* __restrict__ D)
{
    const int gid = blockIdx.x * 256 + threadIdx.x;
    const int off = gid * 8;
    float4 a = *(const float4*)(X + off), b = *(const float4*)(X + off + 4);
    *(short8*)((short*)D + off) = pk8(a, b);
}

// ---------------------------------------------------------------------------
// bf16 MFMA GEMM body (r8-verified): C[m,n] = sum_k A[m,k]*B[n,k] + bias.
// 128xBN tile, BK=32, glds staging, single-buffer, 2 barriers per K-step.
// mode: 0 fp32 flat; 1 bf16 heads [B,H,S,DH]; 2 bf16 heads-T [B,H,DH,S] with
// key-permutation tau within 32-groups (inverse realized by attn PV reads).
// ---------------------------------------------------------------------------
template <int BN>
__device__ __forceinline__ void gemm_body(
    const bf16* __restrict__ A, const bf16* __restrict__ B,
    const float* __restrict__ bias, void* __restrict__ outp,
    int m0, int n0, int mode, int bias_m, float scale)
{
    __shared__ short As[128 * 32];
    __shared__ short Bs[BN * 32];
    constexpr int NI = BN / 32;

    const int tid  = threadIdx.x;
    const int lane = tid & 63;
    const int wv   = tid >> 6;
    const int wm   = (wv >> 1) * 64;
    const int wn   = (wv & 1) * (BN / 2);
    const int fn   = lane & 15;
    const int fq   = lane >> 4;

    const int srow = lane >> 2;
    const int scol = (lane & 3) * 8;

    const short* Ag = (const short*)A;
    const short* Bg = (const short*)B;

    f32x4 acc[4][NI];
#pragma unroll
    for (int i = 0; i < 4; ++i)
#pragma unroll
        for (int j = 0; j < NI; ++j) acc[i][j] = (f32x4){0.f, 0.f, 0.f, 0.f};

    for (int k0 = 0; k0 < DMODEL; k0 += 32) {
#pragma unroll
        for (int i = 0; i < 2; ++i) {
            const int rr = wv * 32 + i * 16;
            const short* ga = Ag + (size_t)(m0 + rr + srow) * DMODEL + k0 + scol;
            GLDS(ga, As + rr * 32);
        }
#pragma unroll
        for (int i = 0; i < BN / 64; ++i) {
            const int rr = wv * (BN / 4) + i * 16;
            const short* gb = Bg + (size_t)(n0 + rr + srow) * DMODEL + k0 + scol;
            GLDS(gb, Bs + rr * 32);
        }
        __syncthreads();

        short8 af[4], bfr[NI];
#pragma unroll
        for (int im = 0; im < 4; ++im)
            af[im] = *(const short8*)(As + (wm + im * 16 + fn) * 32 + fq * 8);
#pragma unroll
        for (int in = 0; in < NI; ++in)
            bfr[in] = *(const short8*)(Bs + (wn + in * 16 + fn) * 32 + fq * 8);
#pragma unroll
        for (int im = 0; im < 4; ++im)
#pragma unroll
            for (int in = 0; in < NI; ++in)
                acc[im][in] = mfma16(af[im], bfr[in], acc[im][in]);
        __syncthreads();
    }

#pragma unroll
    for (int im = 0; im < 4; ++im) {
#pragma unroll
        for (int in = 0; in < NI; ++in) {
#pragma unroll
            for (int r = 0; r < 4; ++r) {
                const int m = m0 + wm + im * 16 + fq * 4 + r;
                const int n = n0 + wn + in * 16 + fn;
                const float c = (acc[im][in][r] + (bias_m ? bias[m] : bias[n])) * scale;
                if (mode == 0) {
                    ((float*)outp)[(size_t)m * DMODEL + n] = c;
                } else if (mode == 1) {
                    const int b = m >> 11, s = m & (SEQ - 1);
                    const int h = n >> 6,  d = n & (DH - 1);
                    ((bf16*)outp)[(((size_t)(b * NHEADS + h) * SEQ) + s) * DH + d] = f2b(c);
                } else {
                    const int h = m >> 6,  d = m & (DH - 1);
                    const int b = n >> 11, s = n & (SEQ - 1);
                    const int p = s & 31;
                    const int sp = (s & ~31) | ((p & 12) << 1) | ((p & 16) >> 2) | (p & 3);
                    ((bf16*)outp)[(((size_t)(b * NHEADS + h) * DH) + d) * SEQ + sp] = f2b(c);
                }
            }
        }
    }
}

__global__ __launch_bounds__(256, 3) void gemm_one(
    const bf16* A, const bf16* B, const float* bias, void* out,
    int mode, int bias_m, float scale)
{
    gemm_body<128>(A, B, bias, out, blockIdx.x * 128, blockIdx.y * 128,
                   mode, bias_m, scale);
}

__global__ __launch_bounds__(256, 3) void gemm_fin(
    const bf16* A, const bf16* B, const float* bias, void* out)
{
    gemm_body<64>(A, B, bias, out, blockIdx.x * 128, blockIdx.y * 64, 0, 0, 1.f);
}

__global__ __launch_bounds__(256, 3) void gemm_qkv(
    const bf16* Qb, const bf16* Kb, const bf16* Vb, const bf16* Wb,
    const float* bq, const float* bk, const float* bv,
    bf16* qp, bf16* kp, bf16* vp)
{
    const int blk = blockIdx.x;
    const int z = blk >> 8, t = blk & 255;
    if (z == 0)
        gemm_body<128>(Qb, Wb,          bq, qp, (t >> 3) * 128, (t & 7) * 128, 1, 0, SCQ);
    else if (z == 1)
        gemm_body<128>(Kb, Wb + M1,     bk, kp, (t >> 3) * 128, (t & 7) * 128, 1, 0, 1.f);
    else
        gemm_body<128>(Wb + 2 * M1, Vb, bv, vp, (t >> 5) * 128, (t & 31) * 128, 2, 1, 1.f);
}

// ---------------------------------------------------------------------------
// Shared attention tile machinery (r9-verified math).
// q,k: [B,H,S,DH] bf16 (q pre-scaled by log2e/8); vt: [B,H,DH,S] bf16,
// key-permuted (tau). Lane (n,quad): queries qg*16+n, C-layout rows=keys.
// ---------------------------------------------------------------------------
struct AttnState {
    f32x4 O[4][2];
    f32x4 lacc[2];
};

// ---------------------------------------------------------------------------
// Split-K attention phase A: 1024 blocks = (bh, qt, kh); each handles 16 of
// the 32 K-tiles. Writes UNNORMALIZED O (bf16) + l (fp32) partials.
// ---------------------------------------------------------------------------
__global__ __launch_bounds__(256, 4) void attn_part(
    const bf16* __restrict__ q,
    const bf16* __restrict__ k,
    const bf16* __restrict__ vt,
    bf16* __restrict__ Op0, bf16* __restrict__ Op1,
    float* __restrict__ lscr)
{
    __shared__ short Kt[2][64 * 64];
    __shared__ short Vt[2][64 * 64];

    const int tid  = threadIdx.x;
    const int wave = tid >> 6;
    const int lane = tid & 63;
    const int n    = lane & 15;
    const int quad = lane >> 4;

    const int blk  = blockIdx.x;          // 0..1023
    const int xcd  = blk & 7;
    const int rest = blk >> 3;            // 0..127
    const int qt   = rest & 15;
    const int kh   = (rest >> 4) & 1;
    const int bh   = ((rest >> 5) << 3) | xcd;
    const int q0w  = qt * 128 + wave * 32;
    const int kt0  = kh * 16;

    const bf16* qhead = q  + (size_t)bh * SEQ * DH;
    const bf16* khead = k  + (size_t)bh * SEQ * DH;
    const bf16* vhead = vt + (size_t)bh * DH * SEQ;

    short8 qf[2][2];
#pragma unroll
    for (int qg = 0; qg < 2; ++qg) {
        const short* qr = (const short*)(qhead + (size_t)(q0w + qg * 16 + n) * DH);
        qf[qg][0] = *(const short8*)(qr + quad * 8);
        qf[qg][1] = *(const short8*)(qr + 32 + quad * 8);
    }

    const short8 onesv = {(short)0x3F80, (short)0x3F80, (short)0x3F80, (short)0x3F80,
                          (short)0x3F80, (short)0x3F80, (short)0x3F80, (short)0x3F80};
    const f32x4 Zv = (f32x4){0.f, 0.f, 0.f, 0.f};

    f32x4 O[4][2];
#pragma unroll
    for (int gd = 0; gd < 4; ++gd)
#pragma unroll
        for (int qg = 0; qg < 2; ++qg) O[gd][qg] = Zv;
    f32x4 lacc[2] = {Zv, Zv};

    const int srow = lane >> 3;
    const int schk = (lane & 7) ^ srow;
    const int off0 = ((quad       ^ (n & 7)) * 8);
    const int off1 = (((4 + quad) ^ (n & 7)) * 8);

    auto stage = [&](int kt, int buf) {
        const int kbase = kt * 64;
#pragma unroll
        for (int i = 0; i < 2; ++i) {
            const int r = wave * 16 + i * 8 + srow;
            const char* gk = (const char*)(khead + (size_t)(kbase + r) * DH) + schk * 16;
            const char* gv = (const char*)(vhead + (size_t)r * SEQ + kbase) + schk * 16;
            GLDS(gk, Kt[buf] + (wave * 16 + i * 8) * 64);
            GLDS(gv, Vt[buf] + (wave * 16 + i * 8) * 64);
        }
    };

    auto tile_body = [&](const short* KtB, const short* VtB) {
        f32x4 st[4][2];
#pragma unroll
        for (int g = 0; g < 4; ++g) {
            const short* kr = KtB + (g * 16 + n) * 64;
            short8 kf0 = *(const short8*)(kr + off0);
            short8 kf1 = *(const short8*)(kr + off1);
#pragma unroll
            for (int qg = 0; qg < 2; ++qg) {
                f32x4 s = mfma16(kf0, qf[qg][0], Zv);
                s = mfma16(kf1, qf[qg][1], s);
                st[g][qg] = s;
            }
        }
        short8 bP[2][2];
#pragma unroll
        for (int t = 0; t < 2; ++t) {
#pragma unroll
            for (int qg = 0; qg < 2; ++qg) {
                union { short8 s8; unsigned u[4]; } bb;
                bb.u[0] = pk2(fexp2(st[2*t][qg][0]),   fexp2(st[2*t][qg][1]));
                bb.u[1] = pk2(fexp2(st[2*t][qg][2]),   fexp2(st[2*t][qg][3]));
                bb.u[2] = pk2(fexp2(st[2*t+1][qg][0]), fexp2(st[2*t+1][qg][1]));
                bb.u[3] = pk2(fexp2(st[2*t+1][qg][2]), fexp2(st[2*t+1][qg][3]));
                bP[t][qg] = bb.s8;
                lacc[qg] = mfma16(onesv, bP[t][qg], lacc[qg]);
            }
        }
#pragma unroll
        for (int gd = 0; gd < 4; ++gd) {
            const short* vr = VtB + (gd * 16 + n) * 64;
            short8 vf0 = *(const short8*)(vr + off0);
            short8 vf1 = *(const short8*)(vr + off1);
#pragma unroll
            for (int qg = 0; qg < 2; ++qg) {
                O[gd][qg] = mfma16(vf0, bP[0][qg], O[gd][qg]);
                O[gd][qg] = mfma16(vf1, bP[1][qg], O[gd][qg]);
            }
        }
    };

    stage(kt0, 0);
#pragma unroll 1
    for (int t = 0; t < 16; t += 2) {
        __syncthreads();
        stage(kt0 + t + 1, 1);
        tile_body(Kt[0], Vt[0]);
        __syncthreads();
        if (t + 2 < 16) stage(kt0 + t + 2, 0);
        tile_body(Kt[1], Vt[1]);
    }

    // ---- epilogue: unnormalized O (bf16) + l (fp32) partials ----
    const int b = bh >> 4;
    const int h = bh & (NHEADS - 1);
    bf16* Op = kh ? Op1 : Op0;
#pragma unroll
    for (int gd = 0; gd < 4; ++gd) {
#pragma unroll
        for (int qg = 0; qg < 2; ++qg) {
            const int s = q0w + qg * 16 + n;
            uint2 o;
            o.x = pk2(O[gd][qg][0], O[gd][qg][1]);
            o.y = pk2(O[gd][qg][2], O[gd][qg][3]);
            *(uint2*)(Op + ((size_t)(b * SEQ + s)) * DMODEL + h * DH + gd * 16 + quad * 4) = o;
        }
    }
    if (quad == 0) {
#pragma unroll
        for (int qg = 0; qg < 2; ++qg)
            lscr[kh * (MROWS * NHEADS / 1) / 1 * 0 + kh * 65536
                 + (b * NHEADS + h) * SEQ + q0w + qg * 16 + n] = lacc[qg][0];
    }
}

// ---------------------------------------------------------------------------
// Split-K merge: out = (O0 + O1) / (l0 + l1), 8 elems/thread.
// ---------------------------------------------------------------------------
__global__ __launch_bounds__(256) void attn_merge(
    const bf16* __restrict__ Op0, const bf16* __restrict__ Op1,
    const float* __restrict__ lscr, bf16* __restrict__ ao)
{
    const int gid = blockIdx.x * 256 + threadIdx.x;     // 524288
    const int e = gid * 8;
    const int row = e >> 10;                // b*SEQ + s
    const int col = e & 1023;
    const int b = row >> 11, s = row & (SEQ - 1), h = col >> 6;
    const int li = (b * NHEADS + h) * SEQ + s;
    const float inv = 1.0f / (lscr[li] + lscr[65536 + li]);

    union { short8 s8; unsigned short us[8]; } a, c;
    a.s8 = *(const short8*)((const short*)Op0 + e);
    c.s8 = *(const short8*)((const short*)Op1 + e);
    float f[8];
#pragma unroll
    for (int i = 0; i < 8; ++i) f[i] = (u2f(a.us[i]) + u2f(c.us[i])) * inv;
    uint4 o;
    o.x = pk2(f[0], f[1]); o.y = pk2(f[2], f[3]);
    o.z = pk2(f[4], f[5]); o.w = pk2(f[6], f[7]);
    *(uint4*)((short*)ao + e) = o;
}

// ---------------------------------------------------------------------------
// Single-kernel attention (r9-verified) — fallback path only.
// ---------------------------------------------------------------------------
__global__ __launch_bounds__(256) void attn_mfma(
    const bf16* __restrict__ q,
    const bf16* __restrict__ k,
    const bf16* __restrict__ vt,
    bf16* __restrict__ out)
{
    __shared__ short Kt[2][64 * 64];
    __shared__ short Vt[2][64 * 64];

    const int tid  = threadIdx.x;
    const int wave = tid >> 6;
    const int lane = tid & 63;
    const int n    = lane & 15;
    const int quad = lane >> 4;

    const int blk  = blockIdx.x;
    const int xcd  = blk & 7;
    const int rest = blk >> 3;
    const int qt   = rest & 15;
    const int bh   = ((rest >> 4) << 3) | xcd;
    const int q0w  = qt * 128 + wave * 32;

    const bf16* qhead = q  + (size_t)bh * SEQ * DH;
    const bf16* khead = k  + (size_t)bh * SEQ * DH;
    const bf16* vhead = vt + (size_t)bh * DH * SEQ;

    short8 qf[2][2];
#pragma unroll
    for (int qg = 0; qg < 2; ++qg) {
        const short* qr = (const short*)(qhead + (size_t)(q0w + qg * 16 + n) * DH);
        qf[qg][0] = *(const short8*)(qr + quad * 8);
        qf[qg][1] = *(const short8*)(qr + 32 + quad * 8);
    }

    const short8 onesv = {(short)0x3F80, (short)0x3F80, (short)0x3F80, (short)0x3F80,
                          (short)0x3F80, (short)0x3F80, (short)0x3F80, (short)0x3F80};
    const f32x4 Zv = (f32x4){0.f, 0.f, 0.f, 0.f};

    f32x4 O[4][2];
#pragma unroll
    for (int gd = 0; gd < 4; ++gd)
#pragma unroll
        for (int qg = 0; qg < 2; ++qg) O[gd][qg] = Zv;
    f32x4 lacc[2] = {Zv, Zv};

    const int srow = lane >> 3;
    const int schk = (lane & 7) ^ srow;
    const int off0 = ((quad       ^ (n & 7)) * 8);
    const int off1 = (((4 + quad) ^ (n & 7)) * 8);

    auto stage = [&](int kt, int buf) {
        const int kbase = kt * 64;
#pragma unroll
        for (int i = 0; i < 2; ++i) {
            const int r = wave * 16 + i * 8 + srow;
            const char* gk = (const char*)(khead + (size_t)(kbase + r) * DH) + schk * 16;
            const char* gv = (const char*)(vhead + (size_t)r * SEQ + kbase) + schk * 16;
            GLDS(gk, Kt[buf] + (wave * 16 + i * 8) * 64);
            GLDS(gv, Vt[buf] + (wave * 16 + i * 8) * 64);
        }
    };

    auto tile_body = [&](const short* KtB, const short* VtB) {
        f32x4 st[4][2];
#pragma unroll
        for (int g = 0; g < 4; ++g) {
            const short* kr = KtB + (g * 16 + n) * 64;
            short8 kf0 = *(const short8*)(kr + off0);
            short8 kf1 = *(const short8*)(kr + off1);
#pragma unroll
            for (int qg = 0; qg < 2; ++qg) {
                f32x4 s = mfma16(kf0, qf[qg][0], Zv);
                s = mfma16(kf1, qf[qg][1], s);
                st[g][qg] = s;
            }
        }
        short8 bP[2][2];
#pragma unroll
        for (int t = 0; t < 2; ++t) {
#pragma unroll
            for (int qg = 0; qg < 2; ++qg) {
                union { short8 s8; unsigned u[4]; } bb;
                bb.u[0] = pk2(fexp2(st[2*t][qg][0]),   fexp2(st[2*t][qg][1]));
                bb.u[1] = pk2(fexp2(st[2*t][qg][2]),   fexp2(st[2*t][qg][3]));
                bb.u[2] = pk2(fexp2(st[2*t+1][qg][0]), fexp2(st[2*t+1][qg][1]));
                bb.u[3] = pk2(fexp2(st[2*t+1][qg][2]), fexp2(st[2*t+1][qg][3]));
                bP[t][qg] = bb.s8;
                lacc[qg] = mfma16(onesv, bP[t][qg], lacc[qg]);
            }
        }
#pragma unroll
        for (int gd = 0; gd < 4; ++gd) {
            const short* vr = VtB + (gd * 16 + n) * 64;
            short8 vf0 = *(const short8*)(vr + off0);
            short8 vf1 = *(const short8*)(vr + off1);
#pragma unroll
            for (int qg = 0; qg < 2; ++qg) {
                O[gd][qg] = mfma16(vf0, bP[0][qg], O[gd][qg]);
                O[gd][qg] = mfma16(vf1, bP[1][qg], O[gd][qg]);
            }
        }
    };

    stage(0, 0);
#pragma unroll 1
    for (int kt = 0; kt < SEQ / 64; kt += 2) {
        __syncthreads();
        stage(kt + 1, 1);
        tile_body(Kt[0], Vt[0]);
        __syncthreads();
        if (kt + 2 < SEQ / 64) stage(kt + 2, 0);
        tile_body(Kt[1], Vt[1]);
    }

    const float inv0 = 1.0f / lacc[0][0];
    const float inv1 = 1.0f / lacc[1][0];
    const int b = bh >> 4;
    const int h = bh & (NHEADS - 1);
#pragma unroll
    for (int gd = 0; gd < 4; ++gd) {
#pragma unroll
        for (int qg = 0; qg < 2; ++qg) {
            const float iv = qg ? inv1 : inv0;
            const int s = q0w + qg * 16 + n;
            uint2 o;
            o.x = pk2(O[gd][qg][0] * iv, O[gd][qg][1] * iv);
            o.y = pk2(O[gd][qg][2] * iv, O[gd][qg][3] * iv);
            *(uint2*)(out + ((size_t)(b * SEQ + s)) * DMODEL + h * DH + gd * 16 + quad * 4) = o;
        }
    }
}

// ---------------------------------------------------------------------------
extern "C" void kernel_launch(void* const* d_in, const int* in_sizes, int n_in,
                              void* d_out, int out_size, void* d_ws, size_t ws_size,
                              hipStream_t stream) {
    const float* Q  = (const float*)d_in[0];
    const float* K  = (const float*)d_in[1];
    const float* V  = (const float*)d_in[2];
    const float* Wq = (const float*)d_in[3];
    const float* Wk = (const float*)d_in[4];
    const float* Wv = (const float*)d_in[5];
    const float* Wo = (const float*)d_in[6];
    const float* bq = (const float*)d_in[7];
    const float* bk = (const float*)d_in[8];
    const float* bv = (const float*)d_in[9];
    const float* bo = (const float*)d_in[10];

    // kp/vp live in d_out (16MB) as scratch; final GEMM rewrites d_out fully.
    bf16* kp = (bf16*)d_out;
    bf16* vp = kp + M4;

    dim3 bb(256);
    dim3 gqk(MROWS / 128, DMODEL / 128);   // (32,8)
    dim3 gvv(DMODEL / 128, MROWS / 128);   // (8,32)
    dim3 gfin(MROWS / 128, DMODEL / 64);   // (32,16)

    if (ws_size >= (size_t)40 * 1024 * 1024) {
        // fused: Wb 8MB | Qb 8 | Kb 8 | Vb 8 | qp 8 = 40MB
        // dead-region reuse after gemm_qkv: Kb->Op0, Vb->Op1, Wq-part of Wb->lscr,
        // Qb->ao (attention output).
        bf16* Wb = (bf16*)d_ws;
        bf16* Qb = Wb + 4 * M1;
        bf16* Kb = Qb + M4;
        bf16* Vb = Kb + M4;
        bf16* qp = Vb + M4;
        bf16* ao = Qb;

        cvt_all<<<8192, bb, 0, stream>>>(Wq, Wk, Wv, Wo, Q, K, V, Wb);
        gemm_qkv<<<768, bb, 0, stream>>>(Qb, Kb, Vb, Wb, bq, bk, bv, qp, kp, vp);
        attn_part<<<1024, bb, 0, stream>>>(qp, kp, vp, Kb, Vb, (float*)Wb);
        attn_merge<<<2048, bb, 0, stream>>>(Kb, Vb, (const float*)Wb, ao);
        gemm_fin<<<gfin, bb, 0, stream>>>(ao, Wb + 3 * M1, bo, d_out);
    } else {
        // sequential: Wb 8 + Xb 8 + qp 8 = 24MB; ao aliases Xb
        bf16* Wb = (bf16*)d_ws;
        bf16* Xb = Wb + 4 * M1;
        bf16* qp = Xb + M4;
        bf16* ao = Xb;

        cvt_w<<<2048, bb, 0, stream>>>(Wq, Wk, Wv, Wo, Wb);
        cvt_1<<<2048, bb, 0, stream>>>(Q, Xb);
        gemm_one<<<gqk, bb, 0, stream>>>(Xb, Wb, bq, qp, 1, 0, SCQ);
        cvt_1<<<2048, bb, 0, stream>>>(K, Xb);
        gemm_one<<<gqk, bb, 0, stream>>>(Xb, Wb + M1, bk, kp, 1, 0, 1.f);
        cvt_1<<<2048, bb, 0, stream>>>(V, Xb);
        gemm_one<<<gvv, bb, 0, stream>>>(Wb + 2 * M1, Xb, bv, vp, 2, 1, 1.f);
        attn_mfma<<<512, bb, 0, stream>>>(qp, kp, vp, ao);
        gemm_fin<<<gfin, bb, 0, stream>>>(ao, Wb + 3 * M1, bo, d_out);
    }
}

// Round 11
// 215.551 us; speedup vs baseline: 1.0613x; 1.0050x over previous
//
#include <hip/hip_runtime.h>
#include <hip/hip_bf16.h>

// MultiHeadAttention  B=2, S=2048, D=1024, H=16, Dh=64  (fp32 I/O)
// Round 11:
//  - gemm_body: BK=64 single-buffer (16 K-steps, half the barriers). LDS rows
//    128B with XOR-chunk swizzle (attention-proven, 0 conflicts). kc-split
//    inner loop to bound VGPR pressure.
//  - attn_part: l-accumulator split into independent MFMA chains.

#define SEQ     2048
#define DMODEL  1024
#define NHEADS  16
#define DH      64
#define MROWS   4096
#define M1      (1024*1024)
#define M4      (4*1024*1024)
#define SCQ     0.18033688f      // log2(e)/sqrt(64)

typedef __hip_bfloat16 bf16;
typedef __attribute__((ext_vector_type(8))) short  short8;  // 8 bf16 = 4 VGPR
typedef __attribute__((ext_vector_type(4))) float  f32x4;   // MFMA C/D

__device__ __forceinline__ bf16 f2b(float x) { return __float2bfloat16(x); }
__device__ __forceinline__ float u2f(unsigned short u) {
    union { unsigned int i; float f; } x; x.i = ((unsigned int)u) << 16; return x.f;
}
__device__ __forceinline__ f32x4 mfma16(short8 a, short8 b, f32x4 c) {
    return __builtin_amdgcn_mfma_f32_16x16x32_bf16(a, b, c, 0, 0, 0);
}
__device__ __forceinline__ unsigned pk2(float a, float b) {
    union { __hip_bfloat162 h; unsigned u; } x;
    x.h = __float22bfloat162_rn(float2{a, b});
    return x.u;
}
__device__ __forceinline__ short8 pk8(float4 a, float4 b) {
    union { short8 s; unsigned u[4]; } x;
    x.u[0] = pk2(a.x, a.y); x.u[1] = pk2(a.z, a.w);
    x.u[2] = pk2(b.x, b.y); x.u[3] = pk2(b.z, b.w);
    return x.s;
}
__device__ __forceinline__ float fexp2(float x) {
    return __builtin_amdgcn_exp2f(x);     // raw v_exp_f32
}
#define GLDS(g, l) __builtin_amdgcn_global_load_lds( \
    (const __attribute__((address_space(1))) void*)(g), \
    (__attribute__((address_space(3))) void*)(l), 16, 0, 0)

// ---------------------------------------------------------------------------
// fp32 -> bf16 conversion kernels
// ---------------------------------------------------------------------------
__global__ __launch_bounds__(256) void cvt_all(
    const float* __restrict__ Wq, const float* __restrict__ Wk,
    const float* __restrict__ Wv, const float* __restrict__ Wo,
    const float* __restrict__ Q,  const float* __restrict__ K,
    const float* __restrict__ V,  bf16* __restrict__ dst)
{
    const size_t gid = (size_t)blockIdx.x * 256 + threadIdx.x;   // 2M threads
    const size_t e0 = gid * 8;
    const float* s;
    if (e0 < (size_t)4 * M1) {
        const float* w[4] = {Wq, Wk, Wv, Wo};
        s = w[e0 >> 20] + (e0 & (M1 - 1));
    } else {
        const float* a[4] = {nullptr, Q, K, V};
        s = a[e0 >> 22] + (e0 & (M4 - 1));
    }
    float4 x = *(const float4*)s, y = *(const float4*)(s + 4);
    *(short8*)((short*)dst + e0) = pk8(x, y);
}

__global__ __launch_bounds__(256) void cvt_w(
    const float* __restrict__ W0, const float* __restrict__ W1,
    const float* __restrict__ W2, const float* __restrict__ W3,
    bf16* __restrict__ dst)
{
    const int gid = blockIdx.x * 256 + threadIdx.x;
    const int t   = gid >> 17;
    const int off = (gid & 131071) * 8;
    const float* srcs[4] = {W0, W1, W2, W3};
    const float* s = srcs[t] + off;
    float4 a = *(const float4*)s, b = *(const float4*)(s + 4);
    *(short8*)((short*)dst + (size_t)gid * 8) = pk8(a, b);
}

__global__ __launch_bounds__(256) void cvt_1(
    const float* __restrict__ X, bf16* __restrict__ D)
{
    const int gid = blockIdx.x * 256 + threadIdx.x;
    const int off = gid * 8;
    float4 a = *(const float4*)(X + off), b = *(const float4*)(X + off + 4);
    *(short8*)((short*)D + off) = pk8(a, b);
}

// ---------------------------------------------------------------------------
// bf16 MFMA GEMM body: C[m,n] = sum_k A[m,k]*B[n,k] + bias. 128xBN tile,
// BK=64 single-buffer (16 K-steps), glds staging into 128B rows with
// XOR-chunk swizzle (conflict-free b128 fragment reads, attention-proven).
// mode: 0 fp32 flat; 1 bf16 heads [B,H,S,DH]; 2 bf16 heads-T [B,H,DH,S] with
// key-permutation tau within 32-groups (inverse realized by attn PV reads).
// ---------------------------------------------------------------------------
template <int BN>
__device__ __forceinline__ void gemm_body(
    const bf16* __restrict__ A, const bf16* __restrict__ B,
    const float* __restrict__ bias, void* __restrict__ outp,
    int m0, int n0, int mode, int bias_m, float scale)
{
    __shared__ short As[128 * 64];   // [m][k], rows 128B, swizzled chunks
    __shared__ short Bs[BN * 64];    // [n][k], rows 128B, swizzled chunks
    constexpr int NI = BN / 32;

    const int tid  = threadIdx.x;
    const int lane = tid & 63;
    const int wv   = tid >> 6;
    const int wm   = (wv >> 1) * 64;
    const int wn   = (wv & 1) * (BN / 2);
    const int fn   = lane & 15;
    const int fq   = lane >> 4;

    const int srow = lane >> 3;               // 0..7 row in 8-row group
    const int schk = (lane & 7) ^ srow;       // swizzled global 16B chunk
    // fragment read offsets (elems): physical chunk = (kc*4+fq) ^ (fn&7)
    const int f0 = ((fq)     ^ (fn & 7)) * 8;
    const int f1 = ((4 + fq) ^ (fn & 7)) * 8;

    const short* Ag = (const short*)A;
    const short* Bg = (const short*)B;

    f32x4 acc[4][NI];
#pragma unroll
    for (int i = 0; i < 4; ++i)
#pragma unroll
        for (int j = 0; j < NI; ++j) acc[i][j] = (f32x4){0.f, 0.f, 0.f, 0.f};

    for (int k0 = 0; k0 < DMODEL; k0 += 64) {
        // ---- stage A (4 glds/wave) and B (BN/32 glds/wave) ----
#pragma unroll
        for (int i = 0; i < 4; ++i) {
            const int rr = wv * 32 + i * 8;
            const short* ga = Ag + (size_t)(m0 + rr + srow) * DMODEL + k0 + schk * 8;
            GLDS(ga, As + rr * 64);
        }
#pragma unroll
        for (int i = 0; i < BN / 32; ++i) {
            const int rr = wv * (BN / 4) + i * 8;
            const short* gb = Bg + (size_t)(n0 + rr + srow) * DMODEL + k0 + schk * 8;
            GLDS(gb, Bs + rr * 64);
        }
        __syncthreads();

        // ---- compute, kc-split to bound live fragments ----
#pragma unroll
        for (int kc = 0; kc < 2; ++kc) {
            const int off = kc ? f1 : f0;
            short8 af[4], bfr[NI];
#pragma unroll
            for (int im = 0; im < 4; ++im)
                af[im] = *(const short8*)(As + (wm + im * 16 + fn) * 64 + off);
#pragma unroll
            for (int in = 0; in < NI; ++in)
                bfr[in] = *(const short8*)(Bs + (wn + in * 16 + fn) * 64 + off);
#pragma unroll
            for (int im = 0; im < 4; ++im)
#pragma unroll
                for (int in = 0; in < NI; ++in)
                    acc[im][in] = mfma16(af[im], bfr[in], acc[im][in]);
        }
        __syncthreads();
    }

#pragma unroll
    for (int im = 0; im < 4; ++im) {
#pragma unroll
        for (int in = 0; in < NI; ++in) {
#pragma unroll
            for (int r = 0; r < 4; ++r) {
                const int m = m0 + wm + im * 16 + fq * 4 + r;
                const int n = n0 + wn + in * 16 + fn;
                const float c = (acc[im][in][r] + (bias_m ? bias[m] : bias[n])) * scale;
                if (mode == 0) {
                    ((float*)outp)[(size_t)m * DMODEL + n] = c;
                } else if (mode == 1) {
                    const int b = m >> 11, s = m & (SEQ - 1);
                    const int h = n >> 6,  d = n & (DH - 1);
                    ((bf16*)outp)[(((size_t)(b * NHEADS + h) * SEQ) + s) * DH + d] = f2b(c);
                } else {
                    const int h = m >> 6,  d = m & (DH - 1);
                    const int b = n >> 11, s = n & (SEQ - 1);
                    const int p = s & 31;
                    const int sp = (s & ~31) | ((p & 12) << 1) | ((p & 16) >> 2) | (p & 3);
                    ((bf16*)outp)[(((size_t)(b * NHEADS + h) * DH) + d) * SEQ + sp] = f2b(c);
                }
            }
        }
    }
}

__global__ __launch_bounds__(256, 3) void gemm_one(
    const bf16* A, const bf16* B, const float* bias, void* out,
    int mode, int bias_m, float scale)
{
    gemm_body<128>(A, B, bias, out, blockIdx.x * 128, blockIdx.y * 128,
                   mode, bias_m, scale);
}

__global__ __launch_bounds__(256, 3) void gemm_fin(
    const bf16* A, const bf16* B, const float* bias, void* out)
{
    gemm_body<64>(A, B, bias, out, blockIdx.x * 128, blockIdx.y * 64, 0, 0, 1.f);
}

__global__ __launch_bounds__(256, 3) void gemm_qkv(
    const bf16* Qb, const bf16* Kb, const bf16* Vb, const bf16* Wb,
    const float* bq, const float* bk, const float* bv,
    bf16* qp, bf16* kp, bf16* vp)
{
    const int blk = blockIdx.x;
    const int z = blk >> 8, t = blk & 255;
    if (z == 0)
        gemm_body<128>(Qb, Wb,          bq, qp, (t >> 3) * 128, (t & 7) * 128, 1, 0, SCQ);
    else if (z == 1)
        gemm_body<128>(Kb, Wb + M1,     bk, kp, (t >> 3) * 128, (t & 7) * 128, 1, 0, 1.f);
    else
        gemm_body<128>(Wb + 2 * M1, Vb, bv, vp, (t >> 5) * 128, (t & 31) * 128, 2, 1, 1.f);
}

// ---------------------------------------------------------------------------
// Split-K attention phase A: 1024 blocks = (bh, qt, kh); each handles 16 of
// the 32 K-tiles. Writes UNNORMALIZED O (bf16) + l (fp32) partials.
// l accumulated via TWO independent ones-row MFMA chains (dep-chain split).
// ---------------------------------------------------------------------------
__global__ __launch_bounds__(256, 4) void attn_part(
    const bf16* __restrict__ q,
    const bf16* __restrict__ k,
    const bf16* __restrict__ vt,
    bf16* __restrict__ Op0, bf16* __restrict__ Op1,
    float* __restrict__ lscr)
{
    __shared__ short Kt[2][64 * 64];
    __shared__ short Vt[2][64 * 64];

    const int tid  = threadIdx.x;
    const int wave = tid >> 6;
    const int lane = tid & 63;
    const int n    = lane & 15;
    const int quad = lane >> 4;

    const int blk  = blockIdx.x;          // 0..1023
    const int xcd  = blk & 7;
    const int rest = blk >> 3;            // 0..127
    const int qt   = rest & 15;
    const int kh   = (rest >> 4) & 1;
    const int bh   = ((rest >> 5) << 3) | xcd;
    const int q0w  = qt * 128 + wave * 32;
    const int kt0  = kh * 16;

    const bf16* qhead = q  + (size_t)bh * SEQ * DH;
    const bf16* khead = k  + (size_t)bh * SEQ * DH;
    const bf16* vhead = vt + (size_t)bh * DH * SEQ;

    short8 qf[2][2];
#pragma unroll
    for (int qg = 0; qg < 2; ++qg) {
        const short* qr = (const short*)(qhead + (size_t)(q0w + qg * 16 + n) * DH);
        qf[qg][0] = *(const short8*)(qr + quad * 8);
        qf[qg][1] = *(const short8*)(qr + 32 + quad * 8);
    }

    const short8 onesv = {(short)0x3F80, (short)0x3F80, (short)0x3F80, (short)0x3F80,
                          (short)0x3F80, (short)0x3F80, (short)0x3F80, (short)0x3F80};
    const f32x4 Zv = (f32x4){0.f, 0.f, 0.f, 0.f};

    f32x4 O[4][2];
#pragma unroll
    for (int gd = 0; gd < 4; ++gd)
#pragma unroll
        for (int qg = 0; qg < 2; ++qg) O[gd][qg] = Zv;
    f32x4 lacc[2][2] = {{Zv, Zv}, {Zv, Zv}};     // [t-chain][qg]

    const int srow = lane >> 3;
    const int schk = (lane & 7) ^ srow;
    const int off0 = ((quad       ^ (n & 7)) * 8);
    const int off1 = (((4 + quad) ^ (n & 7)) * 8);

    auto stage = [&](int kt, int buf) {
        const int kbase = kt * 64;
#pragma unroll
        for (int i = 0; i < 2; ++i) {
            const int r = wave * 16 + i * 8 + srow;
            const char* gk = (const char*)(khead + (size_t)(kbase + r) * DH) + schk * 16;
            const char* gv = (const char*)(vhead + (size_t)r * SEQ + kbase) + schk * 16;
            GLDS(gk, Kt[buf] + (wave * 16 + i * 8) * 64);
            GLDS(gv, Vt[buf] + (wave * 16 + i * 8) * 64);
        }
    };

    auto tile_body = [&](const short* KtB, const short* VtB) {
        f32x4 st[4][2];
#pragma unroll
        for (int g = 0; g < 4; ++g) {
            const short* kr = KtB + (g * 16 + n) * 64;
            short8 kf0 = *(const short8*)(kr + off0);
            short8 kf1 = *(const short8*)(kr + off1);
#pragma unroll
            for (int qg = 0; qg < 2; ++qg) {
                f32x4 s = mfma16(kf0, qf[qg][0], Zv);
                s = mfma16(kf1, qf[qg][1], s);
                st[g][qg] = s;
            }
        }
        short8 bP[2][2];
#pragma unroll
        for (int t = 0; t < 2; ++t) {
#pragma unroll
            for (int qg = 0; qg < 2; ++qg) {
                union { short8 s8; unsigned u[4]; } bb;
                bb.u[0] = pk2(fexp2(st[2*t][qg][0]),   fexp2(st[2*t][qg][1]));
                bb.u[1] = pk2(fexp2(st[2*t][qg][2]),   fexp2(st[2*t][qg][3]));
                bb.u[2] = pk2(fexp2(st[2*t+1][qg][0]), fexp2(st[2*t+1][qg][1]));
                bb.u[3] = pk2(fexp2(st[2*t+1][qg][2]), fexp2(st[2*t+1][qg][3]));
                bP[t][qg] = bb.s8;
                lacc[t][qg] = mfma16(onesv, bP[t][qg], lacc[t][qg]);
            }
        }
#pragma unroll
        for (int gd = 0; gd < 4; ++gd) {
            const short* vr = VtB + (gd * 16 + n) * 64;
            short8 vf0 = *(const short8*)(vr + off0);
            short8 vf1 = *(const short8*)(vr + off1);
#pragma unroll
            for (int qg = 0; qg < 2; ++qg) {
                O[gd][qg] = mfma16(vf0, bP[0][qg], O[gd][qg]);
                O[gd][qg] = mfma16(vf1, bP[1][qg], O[gd][qg]);
            }
        }
    };

    stage(kt0, 0);
#pragma unroll 1
    for (int t = 0; t < 16; t += 2) {
        __syncthreads();
        stage(kt0 + t + 1, 1);
        tile_body(Kt[0], Vt[0]);
        __syncthreads();
        if (t + 2 < 16) stage(kt0 + t + 2, 0);
        tile_body(Kt[1], Vt[1]);
    }

    // ---- epilogue: unnormalized O (bf16) + l (fp32) partials ----
    const int b = bh >> 4;
    const int h = bh & (NHEADS - 1);
    bf16* Op = kh ? Op1 : Op0;
#pragma unroll
    for (int gd = 0; gd < 4; ++gd) {
#pragma unroll
        for (int qg = 0; qg < 2; ++qg) {
            const int s = q0w + qg * 16 + n;
            uint2 o;
            o.x = pk2(O[gd][qg][0], O[gd][qg][1]);
            o.y = pk2(O[gd][qg][2], O[gd][qg][3]);
            *(uint2*)(Op + ((size_t)(b * SEQ + s)) * DMODEL + h * DH + gd * 16 + quad * 4) = o;
        }
    }
    if (quad == 0) {
#pragma unroll
        for (int qg = 0; qg < 2; ++qg)
            lscr[kh * 65536 + (b * NHEADS + h) * SEQ + q0w + qg * 16 + n]
                = lacc[0][qg][0] + lacc[1][qg][0];
    }
}

// ---------------------------------------------------------------------------
// Split-K merge: out = (O0 + O1) / (l0 + l1), 8 elems/thread.
// ---------------------------------------------------------------------------
__global__ __launch_bounds__(256) void attn_merge(
    const bf16* __restrict__ Op0, const bf16* __restrict__ Op1,
    const float* __restrict__ lscr, bf16* __restrict__ ao)
{
    const int gid = blockIdx.x * 256 + threadIdx.x;     // 524288
    const int e = gid * 8;
    const int row = e >> 10;                // b*SEQ + s
    const int col = e & 1023;
    const int b = row >> 11, s = row & (SEQ - 1), h = col >> 6;
    const int li = (b * NHEADS + h) * SEQ + s;
    const float inv = 1.0f / (lscr[li] + lscr[65536 + li]);

    union { short8 s8; unsigned short us[8]; } a, c;
    a.s8 = *(const short8*)((const short*)Op0 + e);
    c.s8 = *(const short8*)((const short*)Op1 + e);
    float f[8];
#pragma unroll
    for (int i = 0; i < 8; ++i) f[i] = (u2f(a.us[i]) + u2f(c.us[i])) * inv;
    uint4 o;
    o.x = pk2(f[0], f[1]); o.y = pk2(f[2], f[3]);
    o.z = pk2(f[4], f[5]); o.w = pk2(f[6], f[7]);
    *(uint4*)((short*)ao + e) = o;
}

// ---------------------------------------------------------------------------
// Single-kernel attention — fallback path only (r9-verified).
// ---------------------------------------------------------------------------
__global__ __launch_bounds__(256) void attn_mfma(
    const bf16* __restrict__ q,
    const bf16* __restrict__ k,
    const bf16* __restrict__ vt,
    bf16* __restrict__ out)
{
    __shared__ short Kt[2][64 * 64];
    __shared__ short Vt[2][64 * 64];

    const int tid  = threadIdx.x;
    const int wave = tid >> 6;
    const int lane = tid & 63;
    const int n    = lane & 15;
    const int quad = lane >> 4;

    const int blk  = blockIdx.x;
    const int xcd  = blk & 7;
    const int rest = blk >> 3;
    const int qt   = rest & 15;
    const int bh   = ((rest >> 4) << 3) | xcd;
    const int q0w  = qt * 128 + wave * 32;

    const bf16* qhead = q  + (size_t)bh * SEQ * DH;
    const bf16* khead = k  + (size_t)bh * SEQ * DH;
    const bf16* vhead = vt + (size_t)bh * DH * SEQ;

    short8 qf[2][2];
#pragma unroll
    for (int qg = 0; qg < 2; ++qg) {
        const short* qr = (const short*)(qhead + (size_t)(q0w + qg * 16 + n) * DH);
        qf[qg][0] = *(const short8*)(qr + quad * 8);
        qf[qg][1] = *(const short8*)(qr + 32 + quad * 8);
    }

    const short8 onesv = {(short)0x3F80, (short)0x3F80, (short)0x3F80, (short)0x3F80,
                          (short)0x3F80, (short)0x3F80, (short)0x3F80, (short)0x3F80};
    const f32x4 Zv = (f32x4){0.f, 0.f, 0.f, 0.f};

    f32x4 O[4][2];
#pragma unroll
    for (int gd = 0; gd < 4; ++gd)
#pragma unroll
        for (int qg = 0; qg < 2; ++qg) O[gd][qg] = Zv;
    f32x4 lacc[2] = {Zv, Zv};

    const int srow = lane >> 3;
    const int schk = (lane & 7) ^ srow;
    const int off0 = ((quad       ^ (n & 7)) * 8);
    const int off1 = (((4 + quad) ^ (n & 7)) * 8);

    auto stage = [&](int kt, int buf) {
        const int kbase = kt * 64;
#pragma unroll
        for (int i = 0; i < 2; ++i) {
            const int r = wave * 16 + i * 8 + srow;
            const char* gk = (const char*)(khead + (size_t)(kbase + r) * DH) + schk * 16;
            const char* gv = (const char*)(vhead + (size_t)r * SEQ + kbase) + schk * 16;
            GLDS(gk, Kt[buf] + (wave * 16 + i * 8) * 64);
            GLDS(gv, Vt[buf] + (wave * 16 + i * 8) * 64);
        }
    };

    auto tile_body = [&](const short* KtB, const short* VtB) {
        f32x4 st[4][2];
#pragma unroll
        for (int g = 0; g < 4; ++g) {
            const short* kr = KtB + (g * 16 + n) * 64;
            short8 kf0 = *(const short8*)(kr + off0);
            short8 kf1 = *(const short8*)(kr + off1);
#pragma unroll
            for (int qg = 0; qg < 2; ++qg) {
                f32x4 s = mfma16(kf0, qf[qg][0], Zv);
                s = mfma16(kf1, qf[qg][1], s);
                st[g][qg] = s;
            }
        }
        short8 bP[2][2];
#pragma unroll
        for (int t = 0; t < 2; ++t) {
#pragma unroll
            for (int qg = 0; qg < 2; ++qg) {
                union { short8 s8; unsigned u[4]; } bb;
                bb.u[0] = pk2(fexp2(st[2*t][qg][0]),   fexp2(st[2*t][qg][1]));
                bb.u[1] = pk2(fexp2(st[2*t][qg][2]),   fexp2(st[2*t][qg][3]));
                bb.u[2] = pk2(fexp2(st[2*t+1][qg][0]), fexp2(st[2*t+1][qg][1]));
                bb.u[3] = pk2(fexp2(st[2*t+1][qg][2]), fexp2(st[2*t+1][qg][3]));
                bP[t][qg] = bb.s8;
                lacc[qg] = mfma16(onesv, bP[t][qg], lacc[qg]);
            }
        }
#pragma unroll
        for (int gd = 0; gd < 4; ++gd) {
            const short* vr = VtB + (gd * 16 + n) * 64;
            short8 vf0 = *(const short8*)(vr + off0);
            short8 vf1 = *(const short8*)(vr + off1);
#pragma unroll
            for (int qg = 0; qg < 2; ++qg) {
                O[gd][qg] = mfma16(vf0, bP[0][qg], O[gd][qg]);
                O[gd][qg] = mfma16(vf1, bP[1][qg], O[gd][qg]);
            }
        }
    };

    stage(0, 0);
#pragma unroll 1
    for (int kt = 0; kt < SEQ / 64; kt += 2) {
        __syncthreads();
        stage(kt + 1, 1);
        tile_body(Kt[0], Vt[0]);
        __syncthreads();
        if (kt + 2 < SEQ / 64) stage(kt + 2, 0);
        tile_body(Kt[1], Vt[1]);
    }

    const float inv0 = 1.0f / lacc[0][0];
    const float inv1 = 1.0f / lacc[1][0];
    const int b = bh >> 4;
    const int h = bh & (NHEADS - 1);
#pragma unroll
    for (int gd = 0; gd < 4; ++gd) {
#pragma unroll
        for (int qg = 0; qg < 2; ++qg) {
            const float iv = qg ? inv1 : inv0;
            const int s = q0w + qg * 16 + n;
            uint2 o;
            o.x = pk2(O[gd][qg][0] * iv, O[gd][qg][1] * iv);
            o.y = pk2(O[gd][qg][2] * iv, O[gd][qg][3] * iv);
            *(uint2*)(out + ((size_t)(b * SEQ + s)) * DMODEL + h * DH + gd * 16 + quad * 4) = o;
        }
    }
}

// ---------------------------------------------------------------------------
extern "C" void kernel_launch(void* const* d_in, const int* in_sizes, int n_in,
                              void* d_out, int out_size, void* d_ws, size_t ws_size,
                              hipStream_t stream) {
    const float* Q  = (const float*)d_in[0];
    const float* K  = (const float*)d_in[1];
    const float* V  = (const float*)d_in[2];
    const float* Wq = (const float*)d_in[3];
    const float* Wk = (const float*)d_in[4];
    const float* Wv = (const float*)d_in[5];
    const float* Wo = (const float*)d_in[6];
    const float* bq = (const float*)d_in[7];
    const float* bk = (const float*)d_in[8];
    const float* bv = (const float*)d_in[9];
    const float* bo = (const float*)d_in[10];

    // kp/vp live in d_out (16MB) as scratch; final GEMM rewrites d_out fully.
    bf16* kp = (bf16*)d_out;
    bf16* vp = kp + M4;

    dim3 bb(256);
    dim3 gqk(MROWS / 128, DMODEL / 128);   // (32,8)
    dim3 gvv(DMODEL / 128, MROWS / 128);   // (8,32)
    dim3 gfin(MROWS / 128, DMODEL / 64);   // (32,16)

    if (ws_size >= (size_t)40 * 1024 * 1024) {
        // fused: Wb 8MB | Qb 8 | Kb 8 | Vb 8 | qp 8 = 40MB
        // dead after gemm_qkv: Kb->Op0, Vb->Op1, Wq-part of Wb->lscr, Qb->ao.
        bf16* Wb = (bf16*)d_ws;
        bf16* Qb = Wb + 4 * M1;
        bf16* Kb = Qb + M4;
        bf16* Vb = Kb + M4;
        bf16* qp = Vb + M4;
        bf16* ao = Qb;

        cvt_all<<<8192, bb, 0, stream>>>(Wq, Wk, Wv, Wo, Q, K, V, Wb);
        gemm_qkv<<<768, bb, 0, stream>>>(Qb, Kb, Vb, Wb, bq, bk, bv, qp, kp, vp);
        attn_part<<<1024, bb, 0, stream>>>(qp, kp, vp, Kb, Vb, (float*)Wb);
        attn_merge<<<2048, bb, 0, stream>>>(Kb, Vb, (const float*)Wb, ao);
        gemm_fin<<<gfin, bb, 0, stream>>>(ao, Wb + 3 * M1, bo, d_out);
    } else {
        // sequential: Wb 8 + Xb 8 + qp 8 = 24MB; ao aliases Xb
        bf16* Wb = (bf16*)d_ws;
        bf16* Xb = Wb + 4 * M1;
        bf16* qp = Xb + M4;
        bf16* ao = Xb;

        cvt_w<<<2048, bb, 0, stream>>>(Wq, Wk, Wv, Wo, Wb);
        cvt_1<<<2048, bb, 0, stream>>>(Q, Xb);
        gemm_one<<<gqk, bb, 0, stream>>>(Xb, Wb, bq, qp, 1, 0, SCQ);
        cvt_1<<<2048, bb, 0, stream>>>(K, Xb);
        gemm_one<<<gqk, bb, 0, stream>>>(Xb, Wb + M1, bk, kp, 1, 0, 1.f);
        cvt_1<<<2048, bb, 0, stream>>>(V, Xb);
        gemm_one<<<gvv, bb, 0, stream>>>(Wb + 2 * M1, Xb, bv, vp, 2, 1, 1.f);
        attn_mfma<<<512, bb, 0, stream>>>(qp, kp, vp, ao);
        gemm_fin<<<gfin, bb, 0, stream>>>(ao, Wb + 3 * M1, bo, d_out);
    }
}

// Round 12
// 210.118 us; speedup vs baseline: 1.0888x; 1.0259x over previous
//
#include <hip/hip_runtime.h>
#include <hip/hip_bf16.h>

// MultiHeadAttention  B=2, S=2048, D=1024, H=16, Dh=64  (fp32 I/O)
// Round 12:
//  - gemm_body reverted to r8 BK=32 (best measured; r11 BK=64 regressed).
//  - attention: split-K merge folded INTO the kernel. 512-thread blocks
//    (8 waves): waves 0-3 = keys 0..1023, waves 4-7 = keys 1024..2047, each
//    half with its own K/V double-buffer (64KB LDS, 2 blocks/CU). Wave w and
//    w+4 hold the SAME 32 queries lane-aligned -> merge via one LDS exchange
//    in fp32. Kills the merge kernel, a launch gap, and 37MB of HBM traffic.

#define SEQ     2048
#define DMODEL  1024
#define NHEADS  16
#define DH      64
#define MROWS   4096
#define M1      (1024*1024)
#define M4      (4*1024*1024)
#define SCQ     0.18033688f      // log2(e)/sqrt(64)

typedef __hip_bfloat16 bf16;
typedef __attribute__((ext_vector_type(8))) short  short8;  // 8 bf16 = 4 VGPR
typedef __attribute__((ext_vector_type(4))) float  f32x4;   // MFMA C/D

__device__ __forceinline__ bf16 f2b(float x) { return __float2bfloat16(x); }
__device__ __forceinline__ float u2f(unsigned short u) {
    union { unsigned int i; float f; } x; x.i = ((unsigned int)u) << 16; return x.f;
}
__device__ __forceinline__ f32x4 mfma16(short8 a, short8 b, f32x4 c) {
    return __builtin_amdgcn_mfma_f32_16x16x32_bf16(a, b, c, 0, 0, 0);
}
__device__ __forceinline__ unsigned pk2(float a, float b) {
    union { __hip_bfloat162 h; unsigned u; } x;
    x.h = __float22bfloat162_rn(float2{a, b});
    return x.u;
}
__device__ __forceinline__ short8 pk8(float4 a, float4 b) {
    union { short8 s; unsigned u[4]; } x;
    x.u[0] = pk2(a.x, a.y); x.u[1] = pk2(a.z, a.w);
    x.u[2] = pk2(b.x, b.y); x.u[3] = pk2(b.z, b.w);
    return x.s;
}
__device__ __forceinline__ float fexp2(float x) {
    return __builtin_amdgcn_exp2f(x);     // raw v_exp_f32
}
#define GLDS(g, l) __builtin_amdgcn_global_load_lds( \
    (const __attribute__((address_space(1))) void*)(g), \
    (__attribute__((address_space(3))) void*)(l), 16, 0, 0)

// ---------------------------------------------------------------------------
// fp32 -> bf16 conversion kernels
// ---------------------------------------------------------------------------
__global__ __launch_bounds__(256) void cvt_all(
    const float* __restrict__ Wq, const float* __restrict__ Wk,
    const float* __restrict__ Wv, const float* __restrict__ Wo,
    const float* __restrict__ Q,  const float* __restrict__ K,
    const float* __restrict__ V,  bf16* __restrict__ dst)
{
    const size_t gid = (size_t)blockIdx.x * 256 + threadIdx.x;   // 2M threads
    const size_t e0 = gid * 8;
    const float* s;
    if (e0 < (size_t)4 * M1) {
        const float* w[4] = {Wq, Wk, Wv, Wo};
        s = w[e0 >> 20] + (e0 & (M1 - 1));
    } else {
        const float* a[4] = {nullptr, Q, K, V};
        s = a[e0 >> 22] + (e0 & (M4 - 1));
    }
    float4 x = *(const float4*)s, y = *(const float4*)(s + 4);
    *(short8*)((short*)dst + e0) = pk8(x, y);
}

__global__ __launch_bounds__(256) void cvt_w(
    const float* __restrict__ W0, const float* __restrict__ W1,
    const float* __restrict__ W2, const float* __restrict__ W3,
    bf16* __restrict__ dst)
{
    const int gid = blockIdx.x * 256 + threadIdx.x;
    const int t   = gid >> 17;
    const int off = (gid & 131071) * 8;
    const float* srcs[4] = {W0, W1, W2, W3};
    const float* s = srcs[t] + off;
    float4 a = *(const float4*)s, b = *(const float4*)(s + 4);
    *(short8*)((short*)dst + (size_t)gid * 8) = pk8(a, b);
}

__global__ __launch_bounds__(256) void cvt_1(
    const float* __restrict__ X, bf16* __restrict__ D)
{
    const int gid = blockIdx.x * 256 + threadIdx.x;
    const int off = gid * 8;
    float4 a = *(const float4*)(X + off), b = *(const float4*)(X + off + 4);
    *(short8*)((short*)D + off) = pk8(a, b);
}

// ---------------------------------------------------------------------------
// bf16 MFMA GEMM body (r8-verified, BK=32 single-buffer, 2 barriers/step).
// mode: 0 fp32 flat; 1 bf16 heads [B,H,S,DH]; 2 bf16 heads-T [B,H,DH,S] with
// key-permutation tau within 32-groups (inverse realized by attn PV reads).
// ---------------------------------------------------------------------------
template <int BN>
__device__ __forceinline__ void gemm_body(
    const bf16* __restrict__ A, const bf16* __restrict__ B,
    const float* __restrict__ bias, void* __restrict__ outp,
    int m0, int n0, int mode, int bias_m, float scale)
{
    __shared__ short As[128 * 32];
    __shared__ short Bs[BN * 32];
    constexpr int NI = BN / 32;

    const int tid  = threadIdx.x;
    const int lane = tid & 63;
    const int wv   = tid >> 6;
    const int wm   = (wv >> 1) * 64;
    const int wn   = (wv & 1) * (BN / 2);
    const int fn   = lane & 15;
    const int fq   = lane >> 4;

    const int srow = lane >> 2;
    const int scol = (lane & 3) * 8;

    const short* Ag = (const short*)A;
    const short* Bg = (const short*)B;

    f32x4 acc[4][NI];
#pragma unroll
    for (int i = 0; i < 4; ++i)
#pragma unroll
        for (int j = 0; j < NI; ++j) acc[i][j] = (f32x4){0.f, 0.f, 0.f, 0.f};

    for (int k0 = 0; k0 < DMODEL; k0 += 32) {
#pragma unroll
        for (int i = 0; i < 2; ++i) {
            const int rr = wv * 32 + i * 16;
            const short* ga = Ag + (size_t)(m0 + rr + srow) * DMODEL + k0 + scol;
            GLDS(ga, As + rr * 32);
        }
#pragma unroll
        for (int i = 0; i < BN / 64; ++i) {
            const int rr = wv * (BN / 4) + i * 16;
            const short* gb = Bg + (size_t)(n0 + rr + srow) * DMODEL + k0 + scol;
            GLDS(gb, Bs + rr * 32);
        }
        __syncthreads();

        short8 af[4], bfr[NI];
#pragma unroll
        for (int im = 0; im < 4; ++im)
            af[im] = *(const short8*)(As + (wm + im * 16 + fn) * 32 + fq * 8);
#pragma unroll
        for (int in = 0; in < NI; ++in)
            bfr[in] = *(const short8*)(Bs + (wn + in * 16 + fn) * 32 + fq * 8);
#pragma unroll
        for (int im = 0; im < 4; ++im)
#pragma unroll
            for (int in = 0; in < NI; ++in)
                acc[im][in] = mfma16(af[im], bfr[in], acc[im][in]);
        __syncthreads();
    }

#pragma unroll
    for (int im = 0; im < 4; ++im) {
#pragma unroll
        for (int in = 0; in < NI; ++in) {
#pragma unroll
            for (int r = 0; r < 4; ++r) {
                const int m = m0 + wm + im * 16 + fq * 4 + r;
                const int n = n0 + wn + in * 16 + fn;
                const float c = (acc[im][in][r] + (bias_m ? bias[m] : bias[n])) * scale;
                if (mode == 0) {
                    ((float*)outp)[(size_t)m * DMODEL + n] = c;
                } else if (mode == 1) {
                    const int b = m >> 11, s = m & (SEQ - 1);
                    const int h = n >> 6,  d = n & (DH - 1);
                    ((bf16*)outp)[(((size_t)(b * NHEADS + h) * SEQ) + s) * DH + d] = f2b(c);
                } else {
                    const int h = m >> 6,  d = m & (DH - 1);
                    const int b = n >> 11, s = n & (SEQ - 1);
                    const int p = s & 31;
                    const int sp = (s & ~31) | ((p & 12) << 1) | ((p & 16) >> 2) | (p & 3);
                    ((bf16*)outp)[(((size_t)(b * NHEADS + h) * DH) + d) * SEQ + sp] = f2b(c);
                }
            }
        }
    }
}

__global__ __launch_bounds__(256, 3) void gemm_one(
    const bf16* A, const bf16* B, const float* bias, void* out,
    int mode, int bias_m, float scale)
{
    gemm_body<128>(A, B, bias, out, blockIdx.x * 128, blockIdx.y * 128,
                   mode, bias_m, scale);
}

__global__ __launch_bounds__(256, 3) void gemm_fin(
    const bf16* A, const bf16* B, const float* bias, void* out)
{
    gemm_body<64>(A, B, bias, out, blockIdx.x * 128, blockIdx.y * 64, 0, 0, 1.f);
}

__global__ __launch_bounds__(256, 3) void gemm_qkv(
    const bf16* Qb, const bf16* Kb, const bf16* Vb, const bf16* Wb,
    const float* bq, const float* bk, const float* bv,
    bf16* qp, bf16* kp, bf16* vp)
{
    const int blk = blockIdx.x;
    const int z = blk >> 8, t = blk & 255;
    if (z == 0)
        gemm_body<128>(Qb, Wb,          bq, qp, (t >> 3) * 128, (t & 7) * 128, 1, 0, SCQ);
    else if (z == 1)
        gemm_body<128>(Kb, Wb + M1,     bk, kp, (t >> 3) * 128, (t & 7) * 128, 1, 0, 1.f);
    else
        gemm_body<128>(Wb + 2 * M1, Vb, bv, vp, (t >> 5) * 128, (t & 31) * 128, 2, 1, 1.f);
}

// ---------------------------------------------------------------------------
// Fused split-K attention: 512 blocks x 512 threads (8 waves).
// Waves 0-3 (half 0): keys 0..1023; waves 4-7 (half 1): keys 1024..2047.
// Each half has private K/V double-buffers (64 KB LDS total, 2 blocks/CU).
// Wave w and w+4 cover the SAME 32 queries lane-aligned -> intra-block merge:
// half 1 dumps fp32 partials (O, l) to LDS; half 0 adds, normalizes, stores.
// q,k: [B,H,S,DH] bf16 (q pre-scaled by log2e/8); vt: [B,H,DH,S] bf16,
// key-permuted (tau). out: concat [B,S,DMODEL] bf16.
// ---------------------------------------------------------------------------
__global__ __launch_bounds__(512, 4) void attn_fused(
    const bf16* __restrict__ q,
    const bf16* __restrict__ k,
    const bf16* __restrict__ vt,
    bf16* __restrict__ out)
{
    __shared__ short LB[32768];      // 64 KB: [half][{K0,K1,V0,V1} x 4096 shorts]

    const int tid  = threadIdx.x;
    const int wave = tid >> 6;           // 0..7
    const int half = wave >> 2;          // key-half
    const int w4   = wave & 3;
    const int lane = tid & 63;
    const int n    = lane & 15;
    const int quad = lane >> 4;

    const int blk  = blockIdx.x;         // 0..511
    const int xcd  = blk & 7;
    const int rest = blk >> 3;           // 0..63
    const int qt   = rest & 15;
    const int bh   = ((rest >> 4) << 3) | xcd;
    const int q0w  = qt * 128 + w4 * 32;
    const int kt0  = half * 16;

    const bf16* qhead = q  + (size_t)bh * SEQ * DH;
    const bf16* khead = k  + (size_t)bh * SEQ * DH;
    const bf16* vhead = vt + (size_t)bh * DH * SEQ;

    short* Kb0 = LB + half * 16384;              // [buf][4096]
    short* Vb0 = LB + half * 16384 + 8192;       // [buf][4096]

    short8 qf[2][2];
#pragma unroll
    for (int qg = 0; qg < 2; ++qg) {
        const short* qr = (const short*)(qhead + (size_t)(q0w + qg * 16 + n) * DH);
        qf[qg][0] = *(const short8*)(qr + quad * 8);
        qf[qg][1] = *(const short8*)(qr + 32 + quad * 8);
    }

    const short8 onesv = {(short)0x3F80, (short)0x3F80, (short)0x3F80, (short)0x3F80,
                          (short)0x3F80, (short)0x3F80, (short)0x3F80, (short)0x3F80};
    const f32x4 Zv = (f32x4){0.f, 0.f, 0.f, 0.f};

    f32x4 O[4][2];
#pragma unroll
    for (int gd = 0; gd < 4; ++gd)
#pragma unroll
        for (int qg = 0; qg < 2; ++qg) O[gd][qg] = Zv;
    f32x4 lacc[2][2] = {{Zv, Zv}, {Zv, Zv}};     // [t-chain][qg]

    const int srow = lane >> 3;
    const int schk = (lane & 7) ^ srow;
    const int off0 = ((quad       ^ (n & 7)) * 8);
    const int off1 = (((4 + quad) ^ (n & 7)) * 8);

    auto stage = [&](int kt, int buf) {
        const int kbase = kt * 64;
#pragma unroll
        for (int i = 0; i < 2; ++i) {
            const int r = w4 * 16 + i * 8 + srow;
            const char* gk = (const char*)(khead + (size_t)(kbase + r) * DH) + schk * 16;
            const char* gv = (const char*)(vhead + (size_t)r * SEQ + kbase) + schk * 16;
            GLDS(gk, Kb0 + buf * 4096 + (w4 * 16 + i * 8) * 64);
            GLDS(gv, Vb0 + buf * 4096 + (w4 * 16 + i * 8) * 64);
        }
    };

    auto tile_body = [&](const short* KtB, const short* VtB) {
        f32x4 st[4][2];
#pragma unroll
        for (int g = 0; g < 4; ++g) {
            const short* kr = KtB + (g * 16 + n) * 64;
            short8 kf0 = *(const short8*)(kr + off0);
            short8 kf1 = *(const short8*)(kr + off1);
#pragma unroll
            for (int qg = 0; qg < 2; ++qg) {
                f32x4 s = mfma16(kf0, qf[qg][0], Zv);
                s = mfma16(kf1, qf[qg][1], s);
                st[g][qg] = s;
            }
        }
        short8 bP[2][2];
#pragma unroll
        for (int t = 0; t < 2; ++t) {
#pragma unroll
            for (int qg = 0; qg < 2; ++qg) {
                union { short8 s8; unsigned u[4]; } bb;
                bb.u[0] = pk2(fexp2(st[2*t][qg][0]),   fexp2(st[2*t][qg][1]));
                bb.u[1] = pk2(fexp2(st[2*t][qg][2]),   fexp2(st[2*t][qg][3]));
                bb.u[2] = pk2(fexp2(st[2*t+1][qg][0]), fexp2(st[2*t+1][qg][1]));
                bb.u[3] = pk2(fexp2(st[2*t+1][qg][2]), fexp2(st[2*t+1][qg][3]));
                bP[t][qg] = bb.s8;
                lacc[t][qg] = mfma16(onesv, bP[t][qg], lacc[t][qg]);
            }
        }
#pragma unroll
        for (int gd = 0; gd < 4; ++gd) {
            const short* vr = VtB + (gd * 16 + n) * 64;
            short8 vf0 = *(const short8*)(vr + off0);
            short8 vf1 = *(const short8*)(vr + off1);
#pragma unroll
            for (int qg = 0; qg < 2; ++qg) {
                O[gd][qg] = mfma16(vf0, bP[0][qg], O[gd][qg]);
                O[gd][qg] = mfma16(vf1, bP[1][qg], O[gd][qg]);
            }
        }
    };

    stage(kt0, 0);
#pragma unroll 1
    for (int t = 0; t < 16; t += 2) {
        __syncthreads();
        stage(kt0 + t + 1, 1);
        tile_body(Kb0, Vb0);
        __syncthreads();
        if (t + 2 < 16) stage(kt0 + t + 2, 0);
        tile_body(Kb0 + 4096, Vb0 + 4096);
    }

    // ---- intra-block split-K merge ----
    // scratch: per lane 34 floats (32 O + 2 l), stride 34 (2-way bank alias =
    // free; 8B aligned for b64). 256 lanes x 136B = 34 KB < 64 KB.
    float* scr = (float*)LB + (size_t)(w4 * 64 + lane) * 34;
    const float l0 = lacc[0][0][0] + lacc[1][0][0];
    const float l1 = lacc[0][1][0] + lacc[1][1][0];

    __syncthreads();                     // all tile reads done; LB reusable
    if (half == 1) {
#pragma unroll
        for (int gd = 0; gd < 4; ++gd)
#pragma unroll
            for (int qg = 0; qg < 2; ++qg) {
                *(float2*)(scr + (gd * 2 + qg) * 4)     = float2{O[gd][qg][0], O[gd][qg][1]};
                *(float2*)(scr + (gd * 2 + qg) * 4 + 2) = float2{O[gd][qg][2], O[gd][qg][3]};
            }
        *(float2*)(scr + 32) = float2{l0, l1};
    }
    __syncthreads();
    if (half == 0) {
        const float2 lo = *(const float2*)(scr + 32);
        const float inv0 = 1.0f / (l0 + lo.x);
        const float inv1 = 1.0f / (l1 + lo.y);
        const int b = bh >> 4;
        const int h = bh & (NHEADS - 1);
#pragma unroll
        for (int gd = 0; gd < 4; ++gd) {
#pragma unroll
            for (int qg = 0; qg < 2; ++qg) {
                const float iv = qg ? inv1 : inv0;
                float2 a = *(const float2*)(scr + (gd * 2 + qg) * 4);
                float2 c = *(const float2*)(scr + (gd * 2 + qg) * 4 + 2);
                const int s = q0w + qg * 16 + n;
                uint2 o;
                o.x = pk2((O[gd][qg][0] + a.x) * iv, (O[gd][qg][1] + a.y) * iv);
                o.y = pk2((O[gd][qg][2] + c.x) * iv, (O[gd][qg][3] + c.y) * iv);
                *(uint2*)(out + ((size_t)(b * SEQ + s)) * DMODEL + h * DH + gd * 16 + quad * 4) = o;
            }
        }
    }
}

// ---------------------------------------------------------------------------
// Single-kernel attention — fallback path only (r9-verified).
// ---------------------------------------------------------------------------
__global__ __launch_bounds__(256) void attn_mfma(
    const bf16* __restrict__ q,
    const bf16* __restrict__ k,
    const bf16* __restrict__ vt,
    bf16* __restrict__ out)
{
    __shared__ short Kt[2][64 * 64];
    __shared__ short Vt[2][64 * 64];

    const int tid  = threadIdx.x;
    const int wave = tid >> 6;
    const int lane = tid & 63;
    const int n    = lane & 15;
    const int quad = lane >> 4;

    const int blk  = blockIdx.x;
    const int xcd  = blk & 7;
    const int rest = blk >> 3;
    const int qt   = rest & 15;
    const int bh   = ((rest >> 4) << 3) | xcd;
    const int q0w  = qt * 128 + wave * 32;

    const bf16* qhead = q  + (size_t)bh * SEQ * DH;
    const bf16* khead = k  + (size_t)bh * SEQ * DH;
    const bf16* vhead = vt + (size_t)bh * DH * SEQ;

    short8 qf[2][2];
#pragma unroll
    for (int qg = 0; qg < 2; ++qg) {
        const short* qr = (const short*)(qhead + (size_t)(q0w + qg * 16 + n) * DH);
        qf[qg][0] = *(const short8*)(qr + quad * 8);
        qf[qg][1] = *(const short8*)(qr + 32 + quad * 8);
    }

    const short8 onesv = {(short)0x3F80, (short)0x3F80, (short)0x3F80, (short)0x3F80,
                          (short)0x3F80, (short)0x3F80, (short)0x3F80, (short)0x3F80};
    const f32x4 Zv = (f32x4){0.f, 0.f, 0.f, 0.f};

    f32x4 O[4][2];
#pragma unroll
    for (int gd = 0; gd < 4; ++gd)
#pragma unroll
        for (int qg = 0; qg < 2; ++qg) O[gd][qg] = Zv;
    f32x4 lacc[2] = {Zv, Zv};

    const int srow = lane >> 3;
    const int schk = (lane & 7) ^ srow;
    const int off0 = ((quad       ^ (n & 7)) * 8);
    const int off1 = (((4 + quad) ^ (n & 7)) * 8);

    auto stage = [&](int kt, int buf) {
        const int kbase = kt * 64;
#pragma unroll
        for (int i = 0; i < 2; ++i) {
            const int r = wave * 16 + i * 8 + srow;
            const char* gk = (const char*)(khead + (size_t)(kbase + r) * DH) + schk * 16;
            const char* gv = (const char*)(vhead + (size_t)r * SEQ + kbase) + schk * 16;
            GLDS(gk, Kt[buf] + (wave * 16 + i * 8) * 64);
            GLDS(gv, Vt[buf] + (wave * 16 + i * 8) * 64);
        }
    };

    auto tile_body = [&](const short* KtB, const short* VtB) {
        f32x4 st[4][2];
#pragma unroll
        for (int g = 0; g < 4; ++g) {
            const short* kr = KtB + (g * 16 + n) * 64;
            short8 kf0 = *(const short8*)(kr + off0);
            short8 kf1 = *(const short8*)(kr + off1);
#pragma unroll
            for (int qg = 0; qg < 2; ++qg) {
                f32x4 s = mfma16(kf0, qf[qg][0], Zv);
                s = mfma16(kf1, qf[qg][1], s);
                st[g][qg] = s;
            }
        }
        short8 bP[2][2];
#pragma unroll
        for (int t = 0; t < 2; ++t) {
#pragma unroll
            for (int qg = 0; qg < 2; ++qg) {
                union { short8 s8; unsigned u[4]; } bb;
                bb.u[0] = pk2(fexp2(st[2*t][qg][0]),   fexp2(st[2*t][qg][1]));
                bb.u[1] = pk2(fexp2(st[2*t][qg][2]),   fexp2(st[2*t][qg][3]));
                bb.u[2] = pk2(fexp2(st[2*t+1][qg][0]), fexp2(st[2*t+1][qg][1]));
                bb.u[3] = pk2(fexp2(st[2*t+1][qg][2]), fexp2(st[2*t+1][qg][3]));
                bP[t][qg] = bb.s8;
                lacc[qg] = mfma16(onesv, bP[t][qg], lacc[qg]);
            }
        }
#pragma unroll
        for (int gd = 0; gd < 4; ++gd) {
            const short* vr = VtB + (gd * 16 + n) * 64;
            short8 vf0 = *(const short8*)(vr + off0);
            short8 vf1 = *(const short8*)(vr + off1);
#pragma unroll
            for (int qg = 0; qg < 2; ++qg) {
                O[gd][qg] = mfma16(vf0, bP[0][qg], O[gd][qg]);
                O[gd][qg] = mfma16(vf1, bP[1][qg], O[gd][qg]);
            }
        }
    };

    stage(0, 0);
#pragma unroll 1
    for (int kt = 0; kt < SEQ / 64; kt += 2) {
        __syncthreads();
        stage(kt + 1, 1);
        tile_body(Kt[0], Vt[0]);
        __syncthreads();
        if (kt + 2 < SEQ / 64) stage(kt + 2, 0);
        tile_body(Kt[1], Vt[1]);
    }

    const float inv0 = 1.0f / lacc[0][0];
    const float inv1 = 1.0f / lacc[1][0];
    const int b = bh >> 4;
    const int h = bh & (NHEADS - 1);
#pragma unroll
    for (int gd = 0; gd < 4; ++gd) {
#pragma unroll
        for (int qg = 0; qg < 2; ++qg) {
            const float iv = qg ? inv1 : inv0;
            const int s = q0w + qg * 16 + n;
            uint2 o;
            o.x = pk2(O[gd][qg][0] * iv, O[gd][qg][1] * iv);
            o.y = pk2(O[gd][qg][2] * iv, O[gd][qg][3] * iv);
            *(uint2*)(out + ((size_t)(b * SEQ + s)) * DMODEL + h * DH + gd * 16 + quad * 4) = o;
        }
    }
}

// ---------------------------------------------------------------------------
extern "C" void kernel_launch(void* const* d_in, const int* in_sizes, int n_in,
                              void* d_out, int out_size, void* d_ws, size_t ws_size,
                              hipStream_t stream) {
    const float* Q  = (const float*)d_in[0];
    const float* K  = (const float*)d_in[1];
    const float* V  = (const float*)d_in[2];
    const float* Wq = (const float*)d_in[3];
    const float* Wk = (const float*)d_in[4];
    const float* Wv = (const float*)d_in[5];
    const float* Wo = (const float*)d_in[6];
    const float* bq = (const float*)d_in[7];
    const float* bk = (const float*)d_in[8];
    const float* bv = (const float*)d_in[9];
    const float* bo = (const float*)d_in[10];

    // kp/vp live in d_out (16MB) as scratch; final GEMM rewrites d_out fully.
    bf16* kp = (bf16*)d_out;
    bf16* vp = kp + M4;

    dim3 bb(256);
    dim3 gqk(MROWS / 128, DMODEL / 128);   // (32,8)
    dim3 gvv(DMODEL / 128, MROWS / 128);   // (8,32)
    dim3 gfin(MROWS / 128, DMODEL / 64);   // (32,16)

    if (ws_size >= (size_t)40 * 1024 * 1024) {
        // fused: Wb 8MB | Qb 8 | Kb 8 | Vb 8 | qp 8 = 40MB; ao aliases Qb.
        bf16* Wb = (bf16*)d_ws;
        bf16* Qb = Wb + 4 * M1;
        bf16* Kb = Qb + M4;
        bf16* Vb = Kb + M4;
        bf16* qp = Vb + M4;
        bf16* ao = Qb;

        cvt_all<<<8192, bb, 0, stream>>>(Wq, Wk, Wv, Wo, Q, K, V, Wb);
        gemm_qkv<<<768, bb, 0, stream>>>(Qb, Kb, Vb, Wb, bq, bk, bv, qp, kp, vp);
        attn_fused<<<512, 512, 0, stream>>>(qp, kp, vp, ao);
        gemm_fin<<<gfin, bb, 0, stream>>>(ao, Wb + 3 * M1, bo, d_out);
    } else {
        // sequential: Wb 8 + Xb 8 + qp 8 = 24MB; ao aliases Xb
        bf16* Wb = (bf16*)d_ws;
        bf16* Xb = Wb + 4 * M1;
        bf16* qp = Xb + M4;
        bf16* ao = Xb;

        cvt_w<<<2048, bb, 0, stream>>>(Wq, Wk, Wv, Wo, Wb);
        cvt_1<<<2048, bb, 0, stream>>>(Q, Xb);
        gemm_one<<<gqk, bb, 0, stream>>>(Xb, Wb, bq, qp, 1, 0, SCQ);
        cvt_1<<<2048, bb, 0, stream>>>(K, Xb);
        gemm_one<<<gqk, bb, 0, stream>>>(Xb, Wb + M1, bk, kp, 1, 0, 1.f);
        cvt_1<<<2048, bb, 0, stream>>>(V, Xb);
        gemm_one<<<gvv, bb, 0, stream>>>(Wb + 2 * M1, Xb, bv, vp, 2, 1, 1.f);
        attn_mfma<<<512, bb, 0, stream>>>(qp, kp, vp, ao);
        gemm_fin<<<gfin, bb, 0, stream>>>(ao, Wb + 3 * M1, bo, d_out);
    }
}